// Round 3
// baseline (1504.243 us; speedup 1.0000x reference)
//
#include <hip/hip_runtime.h>
#include <hip/hip_bf16.h>

// ---------- helpers ----------
__device__ __forceinline__ void atomAddF(float* p, float v) {
  __hip_atomic_fetch_add(p, v, __ATOMIC_RELAXED, __HIP_MEMORY_SCOPE_AGENT);
}

__device__ __forceinline__ int lower_bound_i(const int* a, int n, int key) {
  int lo = 0, hi = n;
  while (lo < hi) { int mid = (lo + hi) >> 1; if (a[mid] < key) lo = mid + 1; else hi = mid; }
  return lo;
}

// ---------- zero fp32 buffer ----------
__global__ void zero_f32(float* p, int n) {
  int i = blockIdx.x * blockDim.x + threadIdx.x;
  if (i < n) p[i] = 0.0f;
}

// ---------- degree / dinv ----------
__global__ void init_deg_u32(unsigned int* deg, int n) {
  int i = blockIdx.x * blockDim.x + threadIdx.x;
  if (i < n) deg[i] = 1u;  // self-loop
}

__global__ void accum_deg(const int* __restrict__ dst, unsigned int* __restrict__ deg, int E) {
  int e = blockIdx.x * blockDim.x + threadIdx.x;
  if (e < E) atomicAdd(&deg[dst[e]], 1u);
}

__global__ void finish_dinv(const unsigned int* __restrict__ deg, float* __restrict__ dinv, int n) {
  int i = blockIdx.x * blockDim.x + threadIdx.x;
  if (i < n) dinv[i] = rsqrtf((float)deg[i]);
}

// ---------- [n,128] @ [128,128] GEMM, fp32 ----------
// block: 256 threads, 32 rows. W fully staged in LDS (64KB) + 32x128 x-tile (16KB).
__global__ __launch_bounds__(256) void gemm128(
    const float* __restrict__ in, const float* __restrict__ W,
    const float* __restrict__ bias, float* __restrict__ out,
    int n, int relu) {
  __shared__ float wp[128 * 128];
  __shared__ float xp[32 * 128];
  int tid = threadIdx.x;
  // stage W (row-major [k][c])
  for (int idx = tid; idx < 128 * 128 / 4; idx += 256) {
    reinterpret_cast<float4*>(wp)[idx] = reinterpret_cast<const float4*>(W)[idx];
  }
  int row0 = blockIdx.x * 32;
  for (int idx = tid; idx < 32 * 128 / 4; idx += 256) {
    int r = idx >> 5;          // 32 float4 per row
    int q = idx & 31;
    int row = row0 + r;
    float4 v = make_float4(0.f, 0.f, 0.f, 0.f);
    if (row < n) v = reinterpret_cast<const float4*>(in)[(size_t)row * 32 + q];
    reinterpret_cast<float4*>(xp)[idx] = v;
  }
  __syncthreads();
  int c = tid & 127;
  int rbase = tid >> 7;  // 0 or 1
  float bv = (bias != nullptr) ? bias[c] : 0.0f;
  for (int p = 0; p < 16; ++p) {
    int r = p * 2 + rbase;
    int row = row0 + r;
    if (row >= n) break;
    float acc = 0.0f;
    const float* xr = &xp[r * 128];
#pragma unroll
    for (int k = 0; k < 128; ++k) acc = fmaf(xr[k], wp[k * 128 + c], acc);
    acc += bv;
    if (relu) acc = fmaxf(acc, 0.0f);
    out[(size_t)row * 128 + c] = acc;
  }
}

// ---------- edge aggregation: agg[dst] += h[src] * dinv[src]*dinv[dst] ----------
// one 64-lane wave per edge; lane handles 2 features (float2)
__global__ __launch_bounds__(256) void edge_agg(
    const int* __restrict__ src, const int* __restrict__ dst,
    const float* __restrict__ dinv, const float* __restrict__ h,
    float* __restrict__ agg, int E) {
  int e = (int)((blockIdx.x * 256u + threadIdx.x) >> 6);
  int lane = threadIdx.x & 63;
  if (e >= E) return;
  int s = src[e], d = dst[e];
  float nrm = dinv[s] * dinv[d];
  float2 hv = reinterpret_cast<const float2*>(h)[(size_t)s * 64 + lane];
  float* ap = agg + (size_t)d * 128 + 2 * lane;
  atomAddF(ap, hv.x * nrm);
  atomAddF(ap + 1, hv.y * nrm);
}

// ---------- self-loop + bias, LayerNorm, ReLU ----------
__global__ __launch_bounds__(256) void agg_ln_relu(
    const float* __restrict__ agg, const float* __restrict__ hself,
    const float* __restrict__ dinv, const float* __restrict__ bias,
    const float* __restrict__ gam, const float* __restrict__ bet,
    float* __restrict__ out, int n) {
  int i = (int)((blockIdx.x * 256u + threadIdx.x) >> 6);
  int lane = threadIdx.x & 63;
  if (i >= n) return;
  float di = dinv[i];
  float sl = di * di;
  float2 av = reinterpret_cast<const float2*>(agg)[(size_t)i * 64 + lane];
  float2 hv = reinterpret_cast<const float2*>(hself)[(size_t)i * 64 + lane];
  float2 bb = reinterpret_cast<const float2*>(bias)[lane];
  float v0 = av.x + hv.x * sl + bb.x;
  float v1 = av.y + hv.y * sl + bb.y;
  float s = v0 + v1, q = v0 * v0 + v1 * v1;
#pragma unroll
  for (int o = 32; o > 0; o >>= 1) {
    s += __shfl_xor(s, o);
    q += __shfl_xor(q, o);
  }
  float m = s * (1.0f / 128.0f);
  float var = q * (1.0f / 128.0f) - m * m;
  float rs = rsqrtf(var + 1e-5f);
  float2 gg = reinterpret_cast<const float2*>(gam)[lane];
  float2 be = reinterpret_cast<const float2*>(bet)[lane];
  float o0 = fmaxf((v0 - m) * rs * gg.x + be.x, 0.0f);
  float o1 = fmaxf((v1 - m) * rs * gg.y + be.y, 0.0f);
  float2 ov; ov.x = o0; ov.y = o1;
  reinterpret_cast<float2*>(out)[(size_t)i * 64 + lane] = ov;
}

// ---------- gate scalar: gate[i] = R[i,:] . gw2 + gb2 ----------
__global__ __launch_bounds__(256) void gate_reduce(
    const float* __restrict__ R, const float* __restrict__ gw2,
    const float* __restrict__ gb2, float* __restrict__ gate, int n) {
  int i = (int)((blockIdx.x * 256u + threadIdx.x) >> 6);
  int lane = threadIdx.x & 63;
  if (i >= n) return;
  float2 rv = reinterpret_cast<const float2*>(R)[(size_t)i * 64 + lane];
  float2 wv = reinterpret_cast<const float2*>(gw2)[lane];
  float s = rv.x * wv.x + rv.y * wv.y;
#pragma unroll
  for (int o = 32; o > 0; o >>= 1) s += __shfl_xor(s, o);
  if (lane == 0) gate[i] = s + gb2[0];
}

// ---------- attention pooling per graph (batch sorted) ----------
__global__ __launch_bounds__(128) void pool_kernel(
    float* __restrict__ gate, const float* __restrict__ h,
    const int* __restrict__ batch, float* __restrict__ pooled, int n) {
  int g = blockIdx.x;
  int tid = threadIdx.x;
  __shared__ float red[128];
  int lo = lower_bound_i(batch, n, g);
  int hi = lower_bound_i(batch, n, g + 1);
  if (lo >= hi) { pooled[(size_t)g * 128 + tid] = 0.0f; return; }
  float m = -3.0e38f;
  for (int i = lo + tid; i < hi; i += 128) m = fmaxf(m, gate[i]);
  red[tid] = m;
  __syncthreads();
#pragma unroll
  for (int o = 64; o > 0; o >>= 1) {
    if (tid < o) red[tid] = fmaxf(red[tid], red[tid + o]);
    __syncthreads();
  }
  m = red[0];
  __syncthreads();
  float s = 0.0f;
  for (int i = lo + tid; i < hi; i += 128) {
    float e = __expf(gate[i] - m);
    gate[i] = e;
    s += e;
  }
  red[tid] = s;
  __syncthreads();
#pragma unroll
  for (int o = 64; o > 0; o >>= 1) {
    if (tid < o) red[tid] += red[tid + o];
    __syncthreads();
  }
  float inv = 1.0f / red[0];
  __syncthreads();
  float acc = 0.0f;
  for (int i = lo; i < hi; ++i)
    acc += gate[i] * h[(size_t)i * 128 + tid];
  pooled[(size_t)g * 128 + tid] = acc * inv;
}

// ---------- classifier: logits = relu(pooled@cw1+cb1)@cw2+cb2 ----------
__global__ __launch_bounds__(128) void classifier(
    const float* __restrict__ pooled, const float* __restrict__ w1,
    const float* __restrict__ b1, const float* __restrict__ w2,
    const float* __restrict__ b2, float* __restrict__ out) {
  int g = blockIdx.x, j = threadIdx.x;
  __shared__ float p[128];
  __shared__ float r[128];
  p[j] = pooled[(size_t)g * 128 + j];
  __syncthreads();
  float acc = 0.0f;
#pragma unroll 8
  for (int k = 0; k < 128; ++k) acc = fmaf(p[k], w1[k * 128 + j], acc);
  acc += b1[j];
  r[j] = fmaxf(acc, 0.0f);
  __syncthreads();
  if (j < 2) {
    float a = 0.0f;
    for (int k = 0; k < 128; ++k) a = fmaf(r[k], w2[k * 2 + j], a);
    out[g * 2 + j] = a + b2[j];
  }
}

static inline size_t alup(size_t x) { return (x + 255) & ~(size_t)255; }

extern "C" void kernel_launch(void* const* d_in, const int* in_sizes, int n_in,
                              void* d_out, int out_size, void* d_ws, size_t ws_size,
                              hipStream_t stream) {
  const float* x    = (const float*)d_in[0];
  const int*   ei   = (const int*)d_in[1];
  const int*   bat  = (const int*)d_in[2];
  const float* W1   = (const float*)d_in[3];
  const float* b1   = (const float*)d_in[4];
  const float* ln1g = (const float*)d_in[5];
  const float* ln1b = (const float*)d_in[6];
  const float* W2   = (const float*)d_in[7];
  const float* b2   = (const float*)d_in[8];
  const float* ln2g = (const float*)d_in[9];
  const float* ln2b = (const float*)d_in[10];
  const float* gw1  = (const float*)d_in[11];
  const float* gb1  = (const float*)d_in[12];
  const float* gw2  = (const float*)d_in[13];
  const float* gb2  = (const float*)d_in[14];
  const float* cw1  = (const float*)d_in[15];
  const float* cb1  = (const float*)d_in[16];
  const float* cw2  = (const float*)d_in[17];
  const float* cb2  = (const float*)d_in[18];

  const int N = in_sizes[2];
  const int E = in_sizes[1] / 2;
  const int G = out_size / 2;
  const int* src = ei;
  const int* dst = ei + E;

  char* base = (char*)d_ws;
  unsigned int* deg = (unsigned int*)base; base += alup((size_t)N * 4);
  float* dinv = (float*)base;              base += alup((size_t)N * 4);
  float* hbuf = (float*)base;              base += alup((size_t)N * 128 * 4);
  float* hout = (float*)base;              base += alup((size_t)N * 128 * 4);
  float* agg  = (float*)base;              base += alup((size_t)N * 128 * 4);
  float* gate = (float*)base;              base += alup((size_t)N * 4);
  float* pooled = (float*)base;            base += alup((size_t)G * 128 * 4);

  float* out = (float*)d_out;

  int nb256 = (N + 255) / 256;
  int eb256 = (E + 255) / 256;
  int gemmB = (N + 31) / 32;
  int waveB_N = (N + 3) / 4;
  int waveB_E = (E + 3) / 4;
  int zeroB = ((N * 128) + 255) / 256;

  // degree -> dinv
  init_deg_u32<<<nb256, 256, 0, stream>>>(deg, N);
  accum_deg<<<eb256, 256, 0, stream>>>(dst, deg, E);
  finish_dinv<<<nb256, 256, 0, stream>>>(deg, dinv, N);

  // ---- layer 1 ----
  gemm128<<<gemmB, 256, 0, stream>>>(x, W1, nullptr, hbuf, N, 0);
  zero_f32<<<zeroB, 256, 0, stream>>>(agg, N * 128);
  edge_agg<<<waveB_E, 256, 0, stream>>>(src, dst, dinv, hbuf, agg, E);
  agg_ln_relu<<<waveB_N, 256, 0, stream>>>(agg, hbuf, dinv, b1, ln1g, ln1b, hout, N);

  // ---- layer 2 ----
  gemm128<<<gemmB, 256, 0, stream>>>(hout, W2, nullptr, hbuf, N, 0);
  zero_f32<<<zeroB, 256, 0, stream>>>(agg, N * 128);
  edge_agg<<<waveB_E, 256, 0, stream>>>(src, dst, dinv, hbuf, agg, E);
  agg_ln_relu<<<waveB_N, 256, 0, stream>>>(agg, hbuf, dinv, b2, ln2g, ln2b, hout, N);

  // ---- gate MLP ----
  gemm128<<<gemmB, 256, 0, stream>>>(hout, gw1, gb1, hbuf, N, 1);
  gate_reduce<<<waveB_N, 256, 0, stream>>>(hbuf, gw2, gb2, gate, N);

  // ---- attention pooling ----
  pool_kernel<<<G, 128, 0, stream>>>(gate, hout, bat, pooled, N);

  // ---- classifier ----
  classifier<<<G, 128, 0, stream>>>(pooled, cw1, cb1, cw2, cb2, out);
}

// Round 4
// 507.261 us; speedup vs baseline: 2.9654x; 2.9654x over previous
//
#include <hip/hip_runtime.h>
#include <hip/hip_bf16.h>

// ---------- helpers ----------
__device__ __forceinline__ int lower_bound_i(const int* a, int n, int key) {
  int lo = 0, hi = n;
  while (lo < hi) { int mid = (lo + hi) >> 1; if (a[mid] < key) lo = mid + 1; else hi = mid; }
  return lo;
}

// ---------- degree / dinv ----------
__global__ void init_deg_u32(unsigned int* deg, int n) {
  int i = blockIdx.x * blockDim.x + threadIdx.x;
  if (i < n) deg[i] = 1u;  // self-loop
}

__global__ void accum_deg(const int* __restrict__ dst, unsigned int* __restrict__ deg, int E) {
  int e = blockIdx.x * blockDim.x + threadIdx.x;
  if (e < E) atomicAdd(&deg[dst[e]], 1u);
}

__global__ void finish_dinv(const unsigned int* __restrict__ deg, float* __restrict__ dinv, int n) {
  int i = blockIdx.x * blockDim.x + threadIdx.x;
  if (i < n) dinv[i] = rsqrtf((float)deg[i]);
}

// ---------- CSR build: exclusive scan of in-edge counts (deg-1) ----------
__global__ __launch_bounds__(256) void scanA(const unsigned int* __restrict__ deg,
                                             int* __restrict__ offs, int* __restrict__ partial, int n) {
  __shared__ int sh[256];
  int t = threadIdx.x;
  int i = blockIdx.x * 256 + t;
  int v = (i < n) ? ((int)deg[i] - 1) : 0;
  sh[t] = v;
  __syncthreads();
  for (int o = 1; o < 256; o <<= 1) {
    int add = (t >= o) ? sh[t - o] : 0;
    __syncthreads();
    sh[t] += add;
    __syncthreads();
  }
  if (i < n) offs[i] = sh[t] - v;            // block-local exclusive
  if (t == 255) partial[blockIdx.x] = sh[255];  // block total
}

__global__ void scanB(int* partial, int nb) {  // serial exclusive scan of block totals
  if (threadIdx.x == 0 && blockIdx.x == 0) {
    int run = 0;
    for (int j = 0; j < nb; ++j) { int v = partial[j]; partial[j] = run; run += v; }
  }
}

__global__ __launch_bounds__(256) void scanC(int* __restrict__ offs, const int* __restrict__ partial,
                                             int* __restrict__ cursor, int n, int E) {
  int i = blockIdx.x * 256 + threadIdx.x;
  if (i < n) {
    int o = offs[i] + partial[i >> 8];
    offs[i] = o;
    cursor[i] = o;
  }
  if (i == 0) offs[n] = E;
}

__global__ __launch_bounds__(256) void scatter_csr(const int* __restrict__ src, const int* __restrict__ dst,
                                                   int* __restrict__ cursor, int* __restrict__ col, int E) {
  int e = blockIdx.x * 256 + threadIdx.x;
  if (e < E) {
    int slot = atomicAdd(&cursor[dst[e]], 1);
    col[slot] = src[e];
  }
}

// ---------- [n,128] @ [128,128] GEMM, fp32, 2x2 register blocking ----------
__global__ __launch_bounds__(256) void gemm128(
    const float* __restrict__ in, const float* __restrict__ W,
    const float* __restrict__ bias, float* __restrict__ out,
    int n, int relu) {
  __shared__ float wp[128 * 128];
  __shared__ float xp[32 * 128];
  int tid = threadIdx.x;
  for (int idx = tid; idx < 128 * 128 / 4; idx += 256)
    reinterpret_cast<float4*>(wp)[idx] = reinterpret_cast<const float4*>(W)[idx];
  int row0 = blockIdx.x * 32;
  for (int idx = tid; idx < 32 * 128 / 4; idx += 256) {
    int r = idx >> 5, q = idx & 31;
    int row = row0 + r;
    float4 v = make_float4(0.f, 0.f, 0.f, 0.f);
    if (row < n) v = reinterpret_cast<const float4*>(in)[(size_t)row * 32 + q];
    reinterpret_cast<float4*>(xp)[idx] = v;
  }
  __syncthreads();
  int c2 = (tid & 63) * 2;   // column pair
  int rq = tid >> 6;         // wave id 0..3 (wave-uniform)
  float2 bv = make_float2(0.f, 0.f);
  if (bias != nullptr) bv = reinterpret_cast<const float2*>(bias)[c2 >> 1];
  for (int p = 0; p < 4; ++p) {
    int r0 = p * 8 + rq * 2, r1 = r0 + 1;
    int row_a = row0 + r0, row_b = row0 + r1;
    if (row_a >= n) break;
    float a00 = 0.f, a01 = 0.f, a10 = 0.f, a11 = 0.f;
    const float* x0 = &xp[r0 * 128];
    const float* x1 = &xp[r1 * 128];
#pragma unroll 16
    for (int k = 0; k < 128; ++k) {
      float xv0 = x0[k];
      float xv1 = x1[k];
      float2 wv = *reinterpret_cast<const float2*>(&wp[k * 128 + c2]);
      a00 = fmaf(xv0, wv.x, a00);
      a01 = fmaf(xv0, wv.y, a01);
      a10 = fmaf(xv1, wv.x, a10);
      a11 = fmaf(xv1, wv.y, a11);
    }
    a00 += bv.x; a01 += bv.y; a10 += bv.x; a11 += bv.y;
    if (relu) {
      a00 = fmaxf(a00, 0.f); a01 = fmaxf(a01, 0.f);
      a10 = fmaxf(a10, 0.f); a11 = fmaxf(a11, 0.f);
    }
    reinterpret_cast<float2*>(out)[(size_t)row_a * 64 + (c2 >> 1)] = make_float2(a00, a01);
    if (row_b < n)
      reinterpret_cast<float2*>(out)[(size_t)row_b * 64 + (c2 >> 1)] = make_float2(a10, a11);
  }
}

// ---------- fused CSR gather + self-loop + bias + LayerNorm + ReLU ----------
// one 64-lane wave per node; lane handles 2 features
__global__ __launch_bounds__(256) void gather_ln(
    const int* __restrict__ offs, const int* __restrict__ col,
    const float* __restrict__ dinv, const float* __restrict__ h,
    const float* __restrict__ bias, const float* __restrict__ gam,
    const float* __restrict__ bet, float* __restrict__ out, int n) {
  int i = (int)((blockIdx.x * 256u + threadIdx.x) >> 6);
  int lane = threadIdx.x & 63;
  if (i >= n) return;
  float di = dinv[i];
  float2 hv = reinterpret_cast<const float2*>(h)[(size_t)i * 64 + lane];
  float2 bb = reinterpret_cast<const float2*>(bias)[lane];
  float sl = di * di;
  float v0 = hv.x * sl + bb.x;
  float v1 = hv.y * sl + bb.y;
  int b0 = offs[i], b1 = offs[i + 1];
  int e = b0;
  for (; e + 2 <= b1; e += 2) {
    int s0 = col[e], s1 = col[e + 1];
    float2 h0 = reinterpret_cast<const float2*>(h)[(size_t)s0 * 64 + lane];
    float2 h1 = reinterpret_cast<const float2*>(h)[(size_t)s1 * 64 + lane];
    float n0 = dinv[s0] * di, n1 = dinv[s1] * di;
    v0 += h0.x * n0 + h1.x * n1;
    v1 += h0.y * n0 + h1.y * n1;
  }
  if (e < b1) {
    int s0 = col[e];
    float2 h0 = reinterpret_cast<const float2*>(h)[(size_t)s0 * 64 + lane];
    float n0 = dinv[s0] * di;
    v0 += h0.x * n0;
    v1 += h0.y * n0;
  }
  // LayerNorm over 128 features (wave reduction)
  float s = v0 + v1, q = v0 * v0 + v1 * v1;
#pragma unroll
  for (int o = 32; o > 0; o >>= 1) {
    s += __shfl_xor(s, o);
    q += __shfl_xor(q, o);
  }
  float m = s * (1.0f / 128.0f);
  float var = q * (1.0f / 128.0f) - m * m;
  float rs = rsqrtf(var + 1e-5f);
  float2 gg = reinterpret_cast<const float2*>(gam)[lane];
  float2 be = reinterpret_cast<const float2*>(bet)[lane];
  float o0 = fmaxf((v0 - m) * rs * gg.x + be.x, 0.0f);
  float o1 = fmaxf((v1 - m) * rs * gg.y + be.y, 0.0f);
  reinterpret_cast<float2*>(out)[(size_t)i * 64 + lane] = make_float2(o0, o1);
}

// ---------- gate scalar: gate[i] = R[i,:] . gw2 + gb2 ----------
__global__ __launch_bounds__(256) void gate_reduce(
    const float* __restrict__ R, const float* __restrict__ gw2,
    const float* __restrict__ gb2, float* __restrict__ gate, int n) {
  int i = (int)((blockIdx.x * 256u + threadIdx.x) >> 6);
  int lane = threadIdx.x & 63;
  if (i >= n) return;
  float2 rv = reinterpret_cast<const float2*>(R)[(size_t)i * 64 + lane];
  float2 wv = reinterpret_cast<const float2*>(gw2)[lane];
  float s = rv.x * wv.x + rv.y * wv.y;
#pragma unroll
  for (int o = 32; o > 0; o >>= 1) s += __shfl_xor(s, o);
  if (lane == 0) gate[i] = s + gb2[0];
}

// ---------- attention pooling per graph (batch sorted) ----------
__global__ __launch_bounds__(128) void pool_kernel(
    float* __restrict__ gate, const float* __restrict__ h,
    const int* __restrict__ batch, float* __restrict__ pooled, int n) {
  int g = blockIdx.x;
  int tid = threadIdx.x;
  __shared__ float red[128];
  int lo = lower_bound_i(batch, n, g);
  int hi = lower_bound_i(batch, n, g + 1);
  if (lo >= hi) { pooled[(size_t)g * 128 + tid] = 0.0f; return; }
  float m = -3.0e38f;
  for (int i = lo + tid; i < hi; i += 128) m = fmaxf(m, gate[i]);
  red[tid] = m;
  __syncthreads();
#pragma unroll
  for (int o = 64; o > 0; o >>= 1) {
    if (tid < o) red[tid] = fmaxf(red[tid], red[tid + o]);
    __syncthreads();
  }
  m = red[0];
  __syncthreads();
  float s = 0.0f;
  for (int i = lo + tid; i < hi; i += 128) {
    float e = __expf(gate[i] - m);
    gate[i] = e;
    s += e;
  }
  red[tid] = s;
  __syncthreads();
#pragma unroll
  for (int o = 64; o > 0; o >>= 1) {
    if (tid < o) red[tid] += red[tid + o];
    __syncthreads();
  }
  float inv = 1.0f / red[0];
  __syncthreads();
  float acc = 0.0f;
  for (int i = lo; i < hi; ++i)
    acc += gate[i] * h[(size_t)i * 128 + tid];
  pooled[(size_t)g * 128 + tid] = acc * inv;
}

// ---------- classifier ----------
__global__ __launch_bounds__(128) void classifier(
    const float* __restrict__ pooled, const float* __restrict__ w1,
    const float* __restrict__ b1, const float* __restrict__ w2,
    const float* __restrict__ b2, float* __restrict__ out) {
  int g = blockIdx.x, j = threadIdx.x;
  __shared__ float p[128];
  __shared__ float r[128];
  p[j] = pooled[(size_t)g * 128 + j];
  __syncthreads();
  float acc = 0.0f;
#pragma unroll 8
  for (int k = 0; k < 128; ++k) acc = fmaf(p[k], w1[k * 128 + j], acc);
  acc += b1[j];
  r[j] = fmaxf(acc, 0.0f);
  __syncthreads();
  if (j < 2) {
    float a = 0.0f;
    for (int k = 0; k < 128; ++k) a = fmaf(r[k], w2[k * 2 + j], a);
    out[g * 2 + j] = a + b2[j];
  }
}

static inline size_t alup(size_t x) { return (x + 255) & ~(size_t)255; }

extern "C" void kernel_launch(void* const* d_in, const int* in_sizes, int n_in,
                              void* d_out, int out_size, void* d_ws, size_t ws_size,
                              hipStream_t stream) {
  const float* x    = (const float*)d_in[0];
  const int*   ei   = (const int*)d_in[1];
  const int*   bat  = (const int*)d_in[2];
  const float* W1   = (const float*)d_in[3];
  const float* b1   = (const float*)d_in[4];
  const float* ln1g = (const float*)d_in[5];
  const float* ln1b = (const float*)d_in[6];
  const float* W2   = (const float*)d_in[7];
  const float* b2   = (const float*)d_in[8];
  const float* ln2g = (const float*)d_in[9];
  const float* ln2b = (const float*)d_in[10];
  const float* gw1  = (const float*)d_in[11];
  const float* gb1  = (const float*)d_in[12];
  const float* gw2  = (const float*)d_in[13];
  const float* gb2  = (const float*)d_in[14];
  const float* cw1  = (const float*)d_in[15];
  const float* cb1  = (const float*)d_in[16];
  const float* cw2  = (const float*)d_in[17];
  const float* cb2  = (const float*)d_in[18];

  const int N = in_sizes[2];
  const int E = in_sizes[1] / 2;
  const int G = out_size / 2;
  const int* src = ei;
  const int* dst = ei + E;

  int nb256 = (N + 255) / 256;
  int eb256 = (E + 255) / 256;
  int gemmB = (N + 31) / 32;
  int waveB_N = (N + 3) / 4;

  char* base = (char*)d_ws;
  unsigned int* deg = (unsigned int*)base; base += alup((size_t)N * 4);
  float* dinv = (float*)base;              base += alup((size_t)N * 4);
  int* offs = (int*)base;                  base += alup((size_t)(N + 1) * 4);
  int* cursor = (int*)base;                base += alup((size_t)N * 4);
  int* partial = (int*)base;               base += alup((size_t)nb256 * 4);
  int* col = (int*)base;                   base += alup((size_t)E * 4);
  float* hbuf = (float*)base;              base += alup((size_t)N * 128 * 4);
  float* hout = (float*)base;              base += alup((size_t)N * 128 * 4);
  float* gate = (float*)base;              base += alup((size_t)N * 4);
  float* pooled = (float*)base;            base += alup((size_t)G * 128 * 4);

  float* out = (float*)d_out;

  // ---- degree -> dinv, CSR build ----
  init_deg_u32<<<nb256, 256, 0, stream>>>(deg, N);
  accum_deg<<<eb256, 256, 0, stream>>>(dst, deg, E);
  finish_dinv<<<nb256, 256, 0, stream>>>(deg, dinv, N);
  scanA<<<nb256, 256, 0, stream>>>(deg, offs, partial, N);
  scanB<<<1, 64, 0, stream>>>(partial, nb256);
  scanC<<<nb256, 256, 0, stream>>>(offs, partial, cursor, N, E);
  scatter_csr<<<eb256, 256, 0, stream>>>(src, dst, cursor, col, E);

  // ---- layer 1 ----
  gemm128<<<gemmB, 256, 0, stream>>>(x, W1, nullptr, hbuf, N, 0);
  gather_ln<<<waveB_N, 256, 0, stream>>>(offs, col, dinv, hbuf, b1, ln1g, ln1b, hout, N);

  // ---- layer 2 ----
  gemm128<<<gemmB, 256, 0, stream>>>(hout, W2, nullptr, hbuf, N, 0);
  gather_ln<<<waveB_N, 256, 0, stream>>>(offs, col, dinv, hbuf, b2, ln2g, ln2b, hout, N);

  // ---- gate MLP ----
  gemm128<<<gemmB, 256, 0, stream>>>(hout, gw1, gb1, hbuf, N, 1);
  gate_reduce<<<waveB_N, 256, 0, stream>>>(hbuf, gw2, gb2, gate, N);

  // ---- attention pooling ----
  pool_kernel<<<G, 128, 0, stream>>>(gate, hout, bat, pooled, N);

  // ---- classifier ----
  classifier<<<G, 128, 0, stream>>>(pooled, cw1, cb1, cw2, cb2, out);
}

// Round 6
// 421.122 us; speedup vs baseline: 3.5720x; 1.2045x over previous
//
#include <hip/hip_runtime.h>
#include <hip/hip_bf16.h>

typedef short s8v __attribute__((ext_vector_type(8)));
typedef float f4v __attribute__((ext_vector_type(4)));

// ---------- bf16 split helpers (RNE) ----------
__device__ __forceinline__ unsigned short f2bf(float f) {
  unsigned int u = __builtin_bit_cast(unsigned int, f);
  unsigned int r = u + 0x7fffu + ((u >> 16) & 1u);
  return (unsigned short)(r >> 16);
}
__device__ __forceinline__ float bf2f(unsigned short s) {
  return __builtin_bit_cast(float, ((unsigned int)s) << 16);
}

__device__ __forceinline__ int lower_bound_i(const int* a, int n, int key) {
  int lo = 0, hi = n;
  while (lo < hi) { int mid = (lo + hi) >> 1; if (a[mid] < key) lo = mid + 1; else hi = mid; }
  return lo;
}

// ---------- degree / dinv ----------
__global__ void init_deg_u32(unsigned int* deg, int n) {
  int i = blockIdx.x * blockDim.x + threadIdx.x;
  if (i < n) deg[i] = 1u;  // self-loop
}

__global__ void accum_deg(const int* __restrict__ dst, unsigned int* __restrict__ deg, int E) {
  int e = blockIdx.x * blockDim.x + threadIdx.x;
  if (e < E) atomicAdd(&deg[dst[e]], 1u);
}

__global__ void finish_dinv(const unsigned int* __restrict__ deg, float* __restrict__ dinv, int n) {
  int i = blockIdx.x * blockDim.x + threadIdx.x;
  if (i < n) dinv[i] = rsqrtf((float)deg[i]);
}

// ---------- CSR build ----------
__global__ __launch_bounds__(256) void scanA(const unsigned int* __restrict__ deg,
                                             int* __restrict__ offs, int* __restrict__ partial, int n) {
  __shared__ int sh[256];
  int t = threadIdx.x;
  int i = blockIdx.x * 256 + t;
  int v = (i < n) ? ((int)deg[i] - 1) : 0;
  sh[t] = v;
  __syncthreads();
  for (int o = 1; o < 256; o <<= 1) {
    int add = (t >= o) ? sh[t - o] : 0;
    __syncthreads();
    sh[t] += add;
    __syncthreads();
  }
  if (i < n) offs[i] = sh[t] - v;
  if (t == 255) partial[blockIdx.x] = sh[255];
}

__global__ void scanB(int* partial, int nb) {
  if (threadIdx.x == 0 && blockIdx.x == 0) {
    int run = 0;
    for (int j = 0; j < nb; ++j) { int v = partial[j]; partial[j] = run; run += v; }
  }
}

__global__ __launch_bounds__(256) void scanC(int* __restrict__ offs, const int* __restrict__ partial,
                                             int* __restrict__ cursor, int n, int E) {
  int i = blockIdx.x * 256 + threadIdx.x;
  if (i < n) {
    int o = offs[i] + partial[i >> 8];
    offs[i] = o;
    cursor[i] = o;
  }
  if (i == 0) offs[n] = E;
}

__global__ __launch_bounds__(256) void scatter_csr(const int* __restrict__ src, const int* __restrict__ dst,
                                                   int* __restrict__ cursor, int* __restrict__ col, int E) {
  int e = blockIdx.x * 256 + threadIdx.x;
  if (e < E) {
    int slot = atomicAdd(&cursor[dst[e]], 1);
    col[slot] = src[e];
  }
}

// ---------- weight pack: fp32 [128x128] -> fragment-ordered split-bf16 ----------
// P layout: group (c,t,lane) of 16 shorts: j0..7 = hi, j8..15 = lo
// element: k = c*32 + (lane>>4)*8 + (j&7), n = t*16 + (lane&15)
__global__ __launch_bounds__(256) void pack_w(const float* __restrict__ W, unsigned short* __restrict__ P) {
  int idx = blockIdx.x * 256 + threadIdx.x;
  if (idx >= 32768) return;
  int j = idx & 15;
  int lane = (idx >> 4) & 63;
  int t = (idx >> 10) & 7;
  int c = (idx >> 13) & 3;
  int k = c * 32 + (lane >> 4) * 8 + (j & 7);
  int n = t * 16 + (lane & 15);
  float f = W[k * 128 + n];
  unsigned short hi = f2bf(f);
  unsigned short outv = (j < 8) ? hi : f2bf(f - bf2f(hi));
  P[idx] = outv;
}

// ---------- MFMA split-bf16 GEMM: [n,128] @ [128,128] ----------
// block = 256 (4 waves); wave = 32 rows x 128 cols; K-chunks of 32
__global__ __launch_bounds__(256) void gemm_mfma(
    const float* __restrict__ in, const unsigned short* __restrict__ P,
    const float* __restrict__ bias, float* __restrict__ out, int n, int relu) {
  __shared__ unsigned short wlds[32768];  // 64 KB = 4096 uint4
  int tid = threadIdx.x;
  for (int i = tid; i < 4096; i += 256)   // FIX R5: was 2048 (staged only half of P)
    reinterpret_cast<uint4*>(wlds)[i] = reinterpret_cast<const uint4*>(P)[i];
  __syncthreads();

  int wave = tid >> 6, lane = tid & 63;
  int quad = lane >> 4, col = lane & 15;
  int base = blockIdx.x * 128 + wave * 32;

  f4v acc[2][8];
#pragma unroll
  for (int rg = 0; rg < 2; ++rg)
#pragma unroll
    for (int t = 0; t < 8; ++t)
      acc[rg][t] = (f4v){0.f, 0.f, 0.f, 0.f};

  for (int c = 0; c < 4; ++c) {
    s8v ah[2], al[2];
#pragma unroll
    for (int rg = 0; rg < 2; ++rg) {
      int m = base + rg * 16 + col;
      float v[8];
      if (m < n) {
        const float4* xp = reinterpret_cast<const float4*>(in + (size_t)m * 128 + c * 32 + quad * 8);
        float4 v0 = xp[0], v1 = xp[1];
        v[0] = v0.x; v[1] = v0.y; v[2] = v0.z; v[3] = v0.w;
        v[4] = v1.x; v[5] = v1.y; v[6] = v1.z; v[7] = v1.w;
      } else {
#pragma unroll
        for (int j = 0; j < 8; ++j) v[j] = 0.f;
      }
#pragma unroll
      for (int j = 0; j < 8; ++j) {
        unsigned short h = f2bf(v[j]);
        ah[rg][j] = (short)h;
        al[rg][j] = (short)f2bf(v[j] - bf2f(h));
      }
    }
#pragma unroll
    for (int t = 0; t < 8; ++t) {
      const s8v* bp = reinterpret_cast<const s8v*>(&wlds[((c * 8 + t) * 64 + lane) * 16]);
      s8v bh = bp[0], bl = bp[1];
#pragma unroll
      for (int rg = 0; rg < 2; ++rg) {
        acc[rg][t] = __builtin_amdgcn_mfma_f32_16x16x32_bf16(ah[rg], bh, acc[rg][t], 0, 0, 0);
        acc[rg][t] = __builtin_amdgcn_mfma_f32_16x16x32_bf16(ah[rg], bl, acc[rg][t], 0, 0, 0);
        acc[rg][t] = __builtin_amdgcn_mfma_f32_16x16x32_bf16(al[rg], bh, acc[rg][t], 0, 0, 0);
      }
    }
  }

  // epilogue: C/D layout row = quad*4+reg, col = lane&15
#pragma unroll
  for (int rg = 0; rg < 2; ++rg) {
#pragma unroll
    for (int t = 0; t < 8; ++t) {
      float bv = (bias != nullptr) ? bias[t * 16 + col] : 0.f;
#pragma unroll
      for (int r = 0; r < 4; ++r) {
        int m = base + rg * 16 + quad * 4 + r;
        if (m < n) {
          float vv = acc[rg][t][r] + bv;
          if (relu) vv = fmaxf(vv, 0.f);
          out[(size_t)m * 128 + t * 16 + col] = vv;
        }
      }
    }
  }
}

// ---------- fused CSR gather + self-loop + bias + LayerNorm + ReLU ----------
__global__ __launch_bounds__(256) void gather_ln(
    const int* __restrict__ offs, const int* __restrict__ col,
    const float* __restrict__ dinv, const float* __restrict__ h,
    const float* __restrict__ bias, const float* __restrict__ gam,
    const float* __restrict__ bet, float* __restrict__ out, int n) {
  int i = (int)((blockIdx.x * 256u + threadIdx.x) >> 6);
  int lane = threadIdx.x & 63;
  if (i >= n) return;
  float di = dinv[i];
  float2 hv = reinterpret_cast<const float2*>(h)[(size_t)i * 64 + lane];
  float2 bb = reinterpret_cast<const float2*>(bias)[lane];
  float sl = di * di;
  float v0 = hv.x * sl + bb.x;
  float v1 = hv.y * sl + bb.y;
  int b0 = offs[i], b1 = offs[i + 1];
  int e = b0;
  for (; e + 2 <= b1; e += 2) {
    int s0 = col[e], s1 = col[e + 1];
    float2 h0 = reinterpret_cast<const float2*>(h)[(size_t)s0 * 64 + lane];
    float2 h1 = reinterpret_cast<const float2*>(h)[(size_t)s1 * 64 + lane];
    float n0 = dinv[s0] * di, n1 = dinv[s1] * di;
    v0 += h0.x * n0 + h1.x * n1;
    v1 += h0.y * n0 + h1.y * n1;
  }
  if (e < b1) {
    int s0 = col[e];
    float2 h0 = reinterpret_cast<const float2*>(h)[(size_t)s0 * 64 + lane];
    float n0 = dinv[s0] * di;
    v0 += h0.x * n0;
    v1 += h0.y * n0;
  }
  float s = v0 + v1, q = v0 * v0 + v1 * v1;
#pragma unroll
  for (int o = 32; o > 0; o >>= 1) {
    s += __shfl_xor(s, o);
    q += __shfl_xor(q, o);
  }
  float m = s * (1.0f / 128.0f);
  float var = q * (1.0f / 128.0f) - m * m;
  float rs = rsqrtf(var + 1e-5f);
  float2 gg = reinterpret_cast<const float2*>(gam)[lane];
  float2 be = reinterpret_cast<const float2*>(bet)[lane];
  float o0 = fmaxf((v0 - m) * rs * gg.x + be.x, 0.0f);
  float o1 = fmaxf((v1 - m) * rs * gg.y + be.y, 0.0f);
  reinterpret_cast<float2*>(out)[(size_t)i * 64 + lane] = make_float2(o0, o1);
}

// ---------- gate scalar ----------
__global__ __launch_bounds__(256) void gate_reduce(
    const float* __restrict__ R, const float* __restrict__ gw2,
    const float* __restrict__ gb2, float* __restrict__ gate, int n) {
  int i = (int)((blockIdx.x * 256u + threadIdx.x) >> 6);
  int lane = threadIdx.x & 63;
  if (i >= n) return;
  float2 rv = reinterpret_cast<const float2*>(R)[(size_t)i * 64 + lane];
  float2 wv = reinterpret_cast<const float2*>(gw2)[lane];
  float s = rv.x * wv.x + rv.y * wv.y;
#pragma unroll
  for (int o = 32; o > 0; o >>= 1) s += __shfl_xor(s, o);
  if (lane == 0) gate[i] = s + gb2[0];
}

// ---------- attention pooling ----------
__global__ __launch_bounds__(128) void pool_kernel(
    float* __restrict__ gate, const float* __restrict__ h,
    const int* __restrict__ batch, float* __restrict__ pooled, int n) {
  int g = blockIdx.x;
  int tid = threadIdx.x;
  __shared__ float red[128];
  int lo = lower_bound_i(batch, n, g);
  int hi = lower_bound_i(batch, n, g + 1);
  if (lo >= hi) { pooled[(size_t)g * 128 + tid] = 0.0f; return; }
  float m = -3.0e38f;
  for (int i = lo + tid; i < hi; i += 128) m = fmaxf(m, gate[i]);
  red[tid] = m;
  __syncthreads();
#pragma unroll
  for (int o = 64; o > 0; o >>= 1) {
    if (tid < o) red[tid] = fmaxf(red[tid], red[tid + o]);
    __syncthreads();
  }
  m = red[0];
  __syncthreads();
  float s = 0.0f;
  for (int i = lo + tid; i < hi; i += 128) {
    float e = __expf(gate[i] - m);
    gate[i] = e;
    s += e;
  }
  red[tid] = s;
  __syncthreads();
#pragma unroll
  for (int o = 64; o > 0; o >>= 1) {
    if (tid < o) red[tid] += red[tid + o];
    __syncthreads();
  }
  float inv = 1.0f / red[0];
  __syncthreads();
  float acc = 0.0f;
  for (int i = lo; i < hi; ++i)
    acc += gate[i] * h[(size_t)i * 128 + tid];
  pooled[(size_t)g * 128 + tid] = acc * inv;
}

// ---------- classifier ----------
__global__ __launch_bounds__(128) void classifier(
    const float* __restrict__ pooled, const float* __restrict__ w1,
    const float* __restrict__ b1, const float* __restrict__ w2,
    const float* __restrict__ b2, float* __restrict__ out) {
  int g = blockIdx.x, j = threadIdx.x;
  __shared__ float p[128];
  __shared__ float r[128];
  p[j] = pooled[(size_t)g * 128 + j];
  __syncthreads();
  float acc = 0.0f;
#pragma unroll 8
  for (int k = 0; k < 128; ++k) acc = fmaf(p[k], w1[k * 128 + j], acc);
  acc += b1[j];
  r[j] = fmaxf(acc, 0.0f);
  __syncthreads();
  if (j < 2) {
    float a = 0.0f;
    for (int k = 0; k < 128; ++k) a = fmaf(r[k], w2[k * 2 + j], a);
    out[g * 2 + j] = a + b2[j];
  }
}

static inline size_t alup(size_t x) { return (x + 255) & ~(size_t)255; }

extern "C" void kernel_launch(void* const* d_in, const int* in_sizes, int n_in,
                              void* d_out, int out_size, void* d_ws, size_t ws_size,
                              hipStream_t stream) {
  const float* x    = (const float*)d_in[0];
  const int*   ei   = (const int*)d_in[1];
  const int*   bat  = (const int*)d_in[2];
  const float* W1   = (const float*)d_in[3];
  const float* b1   = (const float*)d_in[4];
  const float* ln1g = (const float*)d_in[5];
  const float* ln1b = (const float*)d_in[6];
  const float* W2   = (const float*)d_in[7];
  const float* b2   = (const float*)d_in[8];
  const float* ln2g = (const float*)d_in[9];
  const float* ln2b = (const float*)d_in[10];
  const float* gw1  = (const float*)d_in[11];
  const float* gb1  = (const float*)d_in[12];
  const float* gw2  = (const float*)d_in[13];
  const float* gb2  = (const float*)d_in[14];
  const float* cw1  = (const float*)d_in[15];
  const float* cb1  = (const float*)d_in[16];
  const float* cw2  = (const float*)d_in[17];
  const float* cb2  = (const float*)d_in[18];

  const int N = in_sizes[2];
  const int E = in_sizes[1] / 2;
  const int G = out_size / 2;
  const int* src = ei;
  const int* dst = ei + E;

  int nb256 = (N + 255) / 256;
  int eb256 = (E + 255) / 256;
  int mfmaB = (N + 127) / 128;
  int waveB_N = (N + 3) / 4;

  char* base = (char*)d_ws;
  unsigned int* deg = (unsigned int*)base; base += alup((size_t)N * 4);
  float* dinv = (float*)base;              base += alup((size_t)N * 4);
  int* offs = (int*)base;                  base += alup((size_t)(N + 1) * 4);
  int* cursor = (int*)base;                base += alup((size_t)N * 4);
  int* partial = (int*)base;               base += alup((size_t)nb256 * 4);
  int* col = (int*)base;                   base += alup((size_t)E * 4);
  unsigned short* pW1 = (unsigned short*)base; base += alup(32768 * 2);
  unsigned short* pW2 = (unsigned short*)base; base += alup(32768 * 2);
  unsigned short* pG1 = (unsigned short*)base; base += alup(32768 * 2);
  float* hbuf = (float*)base;              base += alup((size_t)N * 128 * 4);
  float* hout = (float*)base;              base += alup((size_t)N * 128 * 4);
  float* gate = (float*)base;              base += alup((size_t)N * 4);
  float* pooled = (float*)base;            base += alup((size_t)G * 128 * 4);

  float* out = (float*)d_out;

  // ---- degree -> dinv, CSR build, weight pack ----
  init_deg_u32<<<nb256, 256, 0, stream>>>(deg, N);
  accum_deg<<<eb256, 256, 0, stream>>>(dst, deg, E);
  finish_dinv<<<nb256, 256, 0, stream>>>(deg, dinv, N);
  scanA<<<nb256, 256, 0, stream>>>(deg, offs, partial, N);
  scanB<<<1, 64, 0, stream>>>(partial, nb256);
  scanC<<<nb256, 256, 0, stream>>>(offs, partial, cursor, N, E);
  scatter_csr<<<eb256, 256, 0, stream>>>(src, dst, cursor, col, E);
  pack_w<<<128, 256, 0, stream>>>(W1, pW1);
  pack_w<<<128, 256, 0, stream>>>(W2, pW2);
  pack_w<<<128, 256, 0, stream>>>(gw1, pG1);

  // ---- layer 1 ----
  gemm_mfma<<<mfmaB, 256, 0, stream>>>(x, pW1, nullptr, hbuf, N, 0);
  gather_ln<<<waveB_N, 256, 0, stream>>>(offs, col, dinv, hbuf, b1, ln1g, ln1b, hout, N);

  // ---- layer 2 ----
  gemm_mfma<<<mfmaB, 256, 0, stream>>>(hout, pW2, nullptr, hbuf, N, 0);
  gather_ln<<<waveB_N, 256, 0, stream>>>(offs, col, dinv, hbuf, b2, ln2g, ln2b, hout, N);

  // ---- gate MLP ----
  gemm_mfma<<<mfmaB, 256, 0, stream>>>(hout, pG1, gb1, hbuf, N, 1);
  gate_reduce<<<waveB_N, 256, 0, stream>>>(hbuf, gw2, gb2, gate, N);

  // ---- attention pooling ----
  pool_kernel<<<G, 128, 0, stream>>>(gate, hout, bat, pooled, N);

  // ---- classifier ----
  classifier<<<G, 128, 0, stream>>>(pooled, cw1, cb1, cw2, cb2, out);
}

// Round 7
// 363.885 us; speedup vs baseline: 4.1338x; 1.1573x over previous
//
#include <hip/hip_runtime.h>
#include <hip/hip_bf16.h>

typedef short s8v __attribute__((ext_vector_type(8)));
typedef float f4v __attribute__((ext_vector_type(4)));

// ---------- bf16 helpers ----------
__device__ __forceinline__ unsigned short f2bf(float f) {  // RNE
  unsigned int u = __builtin_bit_cast(unsigned int, f);
  unsigned int r = u + 0x7fffu + ((u >> 16) & 1u);
  return (unsigned short)(r >> 16);
}
__device__ __forceinline__ float bf2f(unsigned short s) {
  return __builtin_bit_cast(float, ((unsigned int)s) << 16);
}
__device__ __forceinline__ float bflo(unsigned int v) {
  return __builtin_bit_cast(float, (unsigned int)(v << 16));
}
__device__ __forceinline__ float bfhi(unsigned int v) {
  return __builtin_bit_cast(float, (unsigned int)(v & 0xffff0000u));
}
__device__ __forceinline__ unsigned int packbf(float a, float b) {
  return (unsigned int)f2bf(a) | ((unsigned int)f2bf(b) << 16);
}

__device__ __forceinline__ int lower_bound_i(const int* a, int n, int key) {
  int lo = 0, hi = n;
  while (lo < hi) { int mid = (lo + hi) >> 1; if (a[mid] < key) lo = mid + 1; else hi = mid; }
  return lo;
}

// ---------- degree / dinv ----------
__global__ void init_deg_u32(unsigned int* deg, int n) {
  int i = blockIdx.x * blockDim.x + threadIdx.x;
  if (i < n) deg[i] = 1u;
}

__global__ void accum_deg(const int* __restrict__ dst, unsigned int* __restrict__ deg, int E) {
  int e = blockIdx.x * blockDim.x + threadIdx.x;
  if (e < E) atomicAdd(&deg[dst[e]], 1u);
}

__global__ void finish_dinv(const unsigned int* __restrict__ deg, float* __restrict__ dinv, int n) {
  int i = blockIdx.x * blockDim.x + threadIdx.x;
  if (i < n) dinv[i] = rsqrtf((float)deg[i]);
}

// ---------- CSR build ----------
__global__ __launch_bounds__(256) void scanA(const unsigned int* __restrict__ deg,
                                             int* __restrict__ offs, int* __restrict__ partial, int n) {
  __shared__ int sh[256];
  int t = threadIdx.x;
  int i = blockIdx.x * 256 + t;
  int v = (i < n) ? ((int)deg[i] - 1) : 0;
  sh[t] = v;
  __syncthreads();
  for (int o = 1; o < 256; o <<= 1) {
    int add = (t >= o) ? sh[t - o] : 0;
    __syncthreads();
    sh[t] += add;
    __syncthreads();
  }
  if (i < n) offs[i] = sh[t] - v;
  if (t == 255) partial[blockIdx.x] = sh[255];
}

__global__ void scanB(int* partial, int nb) {
  if (threadIdx.x == 0 && blockIdx.x == 0) {
    int run = 0;
    for (int j = 0; j < nb; ++j) { int v = partial[j]; partial[j] = run; run += v; }
  }
}

__global__ __launch_bounds__(256) void scanC(int* __restrict__ offs, const int* __restrict__ partial,
                                             int* __restrict__ cursor, int n, int E) {
  int i = blockIdx.x * 256 + threadIdx.x;
  if (i < n) {
    int o = offs[i] + partial[i >> 8];
    offs[i] = o;
    cursor[i] = o;
  }
  if (i == 0) offs[n] = E;
}

__global__ __launch_bounds__(256) void scatter_csr(const int* __restrict__ src, const int* __restrict__ dst,
                                                   int* __restrict__ cursor, int* __restrict__ col, int E) {
  int e = blockIdx.x * 256 + threadIdx.x;
  if (e < E) {
    int slot = atomicAdd(&cursor[dst[e]], 1);
    col[slot] = src[e];
  }
}

// ---------- weight pack: fp32 [128x128] -> fragment-ordered split-bf16 ----------
__global__ __launch_bounds__(256) void pack_w(const float* __restrict__ W, unsigned short* __restrict__ P) {
  int idx = blockIdx.x * 256 + threadIdx.x;
  if (idx >= 32768) return;
  int j = idx & 15;
  int lane = (idx >> 4) & 63;
  int t = (idx >> 10) & 7;
  int c = (idx >> 13) & 3;
  int k = c * 32 + (lane >> 4) * 8 + (j & 7);
  int n = t * 16 + (lane & 15);
  float f = W[k * 128 + n];
  unsigned short hi = f2bf(f);
  unsigned short outv = (j < 8) ? hi : f2bf(f - bf2f(hi));
  P[idx] = outv;
}

// ---------- L1 GEMM: fp32 in (split-A, 3 MFMA), bf16 out ----------
__global__ __launch_bounds__(256) void gemm_f32in(
    const float* __restrict__ in, const unsigned short* __restrict__ P,
    unsigned short* __restrict__ out, int n) {
  __shared__ unsigned short wlds[32768];
  int tid = threadIdx.x;
  for (int i = tid; i < 4096; i += 256)
    reinterpret_cast<uint4*>(wlds)[i] = reinterpret_cast<const uint4*>(P)[i];
  __syncthreads();

  int wave = tid >> 6, lane = tid & 63;
  int quad = lane >> 4, col = lane & 15;
  int base = blockIdx.x * 128 + wave * 32;

  f4v acc[2][8];
#pragma unroll
  for (int rg = 0; rg < 2; ++rg)
#pragma unroll
    for (int t = 0; t < 8; ++t) acc[rg][t] = (f4v){0.f, 0.f, 0.f, 0.f};

  for (int c = 0; c < 4; ++c) {
    s8v ah[2], al[2];
#pragma unroll
    for (int rg = 0; rg < 2; ++rg) {
      int m = base + rg * 16 + col;
      float v[8];
      if (m < n) {
        const float4* xp = reinterpret_cast<const float4*>(in + (size_t)m * 128 + c * 32 + quad * 8);
        float4 v0 = xp[0], v1 = xp[1];
        v[0] = v0.x; v[1] = v0.y; v[2] = v0.z; v[3] = v0.w;
        v[4] = v1.x; v[5] = v1.y; v[6] = v1.z; v[7] = v1.w;
      } else {
#pragma unroll
        for (int j = 0; j < 8; ++j) v[j] = 0.f;
      }
#pragma unroll
      for (int j = 0; j < 8; ++j) {
        unsigned short h = f2bf(v[j]);
        ah[rg][j] = (short)h;
        al[rg][j] = (short)f2bf(v[j] - bf2f(h));
      }
    }
#pragma unroll
    for (int t = 0; t < 8; ++t) {
      const s8v* bp = reinterpret_cast<const s8v*>(&wlds[((c * 8 + t) * 64 + lane) * 16]);
      s8v bh = bp[0], bl = bp[1];
#pragma unroll
      for (int rg = 0; rg < 2; ++rg) {
        acc[rg][t] = __builtin_amdgcn_mfma_f32_16x16x32_bf16(ah[rg], bh, acc[rg][t], 0, 0, 0);
        acc[rg][t] = __builtin_amdgcn_mfma_f32_16x16x32_bf16(ah[rg], bl, acc[rg][t], 0, 0, 0);
        acc[rg][t] = __builtin_amdgcn_mfma_f32_16x16x32_bf16(al[rg], bh, acc[rg][t], 0, 0, 0);
      }
    }
  }
#pragma unroll
  for (int rg = 0; rg < 2; ++rg)
#pragma unroll
    for (int t = 0; t < 8; ++t)
#pragma unroll
      for (int r = 0; r < 4; ++r) {
        int m = base + rg * 16 + quad * 4 + r;
        if (m < n) out[(size_t)m * 128 + t * 16 + col] = f2bf(acc[rg][t][r]);
      }
}

// ---------- bf16-in GEMM (A direct, 2 MFMA), bf16 out ----------
__global__ __launch_bounds__(256) void gemm_b16in(
    const unsigned short* __restrict__ in, const unsigned short* __restrict__ P,
    unsigned short* __restrict__ out, int n) {
  __shared__ unsigned short wlds[32768];
  int tid = threadIdx.x;
  for (int i = tid; i < 4096; i += 256)
    reinterpret_cast<uint4*>(wlds)[i] = reinterpret_cast<const uint4*>(P)[i];
  __syncthreads();

  int wave = tid >> 6, lane = tid & 63;
  int quad = lane >> 4, col = lane & 15;
  int base = blockIdx.x * 128 + wave * 32;

  f4v acc[2][8];
#pragma unroll
  for (int rg = 0; rg < 2; ++rg)
#pragma unroll
    for (int t = 0; t < 8; ++t) acc[rg][t] = (f4v){0.f, 0.f, 0.f, 0.f};

  for (int c = 0; c < 4; ++c) {
    s8v ah[2];
#pragma unroll
    for (int rg = 0; rg < 2; ++rg) {
      int m = base + rg * 16 + col;
      if (m < n)
        ah[rg] = *reinterpret_cast<const s8v*>(in + (size_t)m * 128 + c * 32 + quad * 8);
      else
        ah[rg] = (s8v){0, 0, 0, 0, 0, 0, 0, 0};
    }
#pragma unroll
    for (int t = 0; t < 8; ++t) {
      const s8v* bp = reinterpret_cast<const s8v*>(&wlds[((c * 8 + t) * 64 + lane) * 16]);
      s8v bh = bp[0], bl = bp[1];
#pragma unroll
      for (int rg = 0; rg < 2; ++rg) {
        acc[rg][t] = __builtin_amdgcn_mfma_f32_16x16x32_bf16(ah[rg], bh, acc[rg][t], 0, 0, 0);
        acc[rg][t] = __builtin_amdgcn_mfma_f32_16x16x32_bf16(ah[rg], bl, acc[rg][t], 0, 0, 0);
      }
    }
  }
#pragma unroll
  for (int rg = 0; rg < 2; ++rg)
#pragma unroll
    for (int t = 0; t < 8; ++t)
#pragma unroll
      for (int r = 0; r < 4; ++r) {
        int m = base + rg * 16 + quad * 4 + r;
        if (m < n) out[(size_t)m * 128 + t * 16 + col] = f2bf(acc[rg][t][r]);
      }
}

// ---------- gate GEMM: bf16 in, fused relu + dot(gw2) + reduce -> gate[N] fp32 ----------
__global__ __launch_bounds__(256) void gemm_gate(
    const unsigned short* __restrict__ in, const unsigned short* __restrict__ P,
    const float* __restrict__ gb1, const float* __restrict__ gw2,
    const float* __restrict__ gb2, float* __restrict__ gate, int n) {
  __shared__ unsigned short wlds[32768];
  int tid = threadIdx.x;
  for (int i = tid; i < 4096; i += 256)
    reinterpret_cast<uint4*>(wlds)[i] = reinterpret_cast<const uint4*>(P)[i];
  __syncthreads();

  int wave = tid >> 6, lane = tid & 63;
  int quad = lane >> 4, col = lane & 15;
  int base = blockIdx.x * 128 + wave * 32;

  f4v acc[2][8];
#pragma unroll
  for (int rg = 0; rg < 2; ++rg)
#pragma unroll
    for (int t = 0; t < 8; ++t) acc[rg][t] = (f4v){0.f, 0.f, 0.f, 0.f};

  for (int c = 0; c < 4; ++c) {
    s8v ah[2];
#pragma unroll
    for (int rg = 0; rg < 2; ++rg) {
      int m = base + rg * 16 + col;
      if (m < n)
        ah[rg] = *reinterpret_cast<const s8v*>(in + (size_t)m * 128 + c * 32 + quad * 8);
      else
        ah[rg] = (s8v){0, 0, 0, 0, 0, 0, 0, 0};
    }
#pragma unroll
    for (int t = 0; t < 8; ++t) {
      const s8v* bp = reinterpret_cast<const s8v*>(&wlds[((c * 8 + t) * 64 + lane) * 16]);
      s8v bh = bp[0], bl = bp[1];
#pragma unroll
      for (int rg = 0; rg < 2; ++rg) {
        acc[rg][t] = __builtin_amdgcn_mfma_f32_16x16x32_bf16(ah[rg], bh, acc[rg][t], 0, 0, 0);
        acc[rg][t] = __builtin_amdgcn_mfma_f32_16x16x32_bf16(ah[rg], bl, acc[rg][t], 0, 0, 0);
      }
    }
  }
  // fused epilogue: gate[m] = sum_c relu(R[m,c]) * gw2[c] + gb2
  float bv[8], g2[8];
#pragma unroll
  for (int t = 0; t < 8; ++t) {
    bv[t] = gb1[t * 16 + col];
    g2[t] = gw2[t * 16 + col];
  }
  float gb2v = gb2[0];
#pragma unroll
  for (int rg = 0; rg < 2; ++rg)
#pragma unroll
    for (int r = 0; r < 4; ++r) {
      float p = 0.f;
#pragma unroll
      for (int t = 0; t < 8; ++t)
        p += fmaxf(acc[rg][t][r] + bv[t], 0.f) * g2[t];
#pragma unroll
      for (int o = 1; o < 16; o <<= 1) p += __shfl_xor(p, o);
      int m = base + rg * 16 + quad * 4 + r;
      if (col == 0 && m < n) gate[m] = p + gb2v;
    }
}

// ---------- fused CSR gather + self-loop + bias + LayerNorm + ReLU (bf16 io) ----------
__global__ __launch_bounds__(256) void gather_ln(
    const int* __restrict__ offs, const int* __restrict__ col,
    const float* __restrict__ dinv, const unsigned short* __restrict__ h,
    const float* __restrict__ bias, const float* __restrict__ gam,
    const float* __restrict__ bet, unsigned short* __restrict__ out, int n) {
  int i = (int)((blockIdx.x * 256u + threadIdx.x) >> 6);
  int lane = threadIdx.x & 63;
  if (i >= n) return;
  const unsigned int* hu = reinterpret_cast<const unsigned int*>(h);
  float di = dinv[i];
  unsigned int hv = hu[(size_t)i * 64 + lane];
  float2 bb = reinterpret_cast<const float2*>(bias)[lane];
  float sl = di * di;
  float v0 = bflo(hv) * sl + bb.x;
  float v1 = bfhi(hv) * sl + bb.y;
  int b0 = offs[i], b1 = offs[i + 1];
  int e = b0;
  for (; e + 2 <= b1; e += 2) {
    int s0 = col[e], s1 = col[e + 1];
    unsigned int h0 = hu[(size_t)s0 * 64 + lane];
    unsigned int h1 = hu[(size_t)s1 * 64 + lane];
    float n0 = dinv[s0] * di, n1 = dinv[s1] * di;
    v0 += bflo(h0) * n0 + bflo(h1) * n1;
    v1 += bfhi(h0) * n0 + bfhi(h1) * n1;
  }
  if (e < b1) {
    int s0 = col[e];
    unsigned int h0 = hu[(size_t)s0 * 64 + lane];
    float n0 = dinv[s0] * di;
    v0 += bflo(h0) * n0;
    v1 += bfhi(h0) * n0;
  }
  float s = v0 + v1, q = v0 * v0 + v1 * v1;
#pragma unroll
  for (int o = 32; o > 0; o >>= 1) {
    s += __shfl_xor(s, o);
    q += __shfl_xor(q, o);
  }
  float m = s * (1.0f / 128.0f);
  float var = q * (1.0f / 128.0f) - m * m;
  float rs = rsqrtf(var + 1e-5f);
  float2 gg = reinterpret_cast<const float2*>(gam)[lane];
  float2 be = reinterpret_cast<const float2*>(bet)[lane];
  float o0 = fmaxf((v0 - m) * rs * gg.x + be.x, 0.0f);
  float o1 = fmaxf((v1 - m) * rs * gg.y + be.y, 0.0f);
  reinterpret_cast<unsigned int*>(out)[(size_t)i * 64 + lane] = packbf(o0, o1);
}

// ---------- attention pooling (bf16 h), 256 threads ----------
__global__ __launch_bounds__(256) void pool_kernel(
    float* __restrict__ gate, const unsigned short* __restrict__ h,
    const int* __restrict__ batch, float* __restrict__ pooled, int n) {
  int g = blockIdx.x;
  int tid = threadIdx.x;
  __shared__ float red[256];
  int lo = lower_bound_i(batch, n, g);
  int hi = lower_bound_i(batch, n, g + 1);
  if (lo >= hi) {
    if (tid < 128) pooled[(size_t)g * 128 + tid] = 0.0f;
    return;
  }
  float m = -3.0e38f;
  for (int i = lo + tid; i < hi; i += 256) m = fmaxf(m, gate[i]);
  red[tid] = m;
  __syncthreads();
#pragma unroll
  for (int o = 128; o > 0; o >>= 1) {
    if (tid < o) red[tid] = fmaxf(red[tid], red[tid + o]);
    __syncthreads();
  }
  m = red[0];
  __syncthreads();
  float s = 0.0f;
  for (int i = lo + tid; i < hi; i += 256) {
    float e = __expf(gate[i] - m);
    gate[i] = e;
    s += e;
  }
  red[tid] = s;
  __syncthreads();
#pragma unroll
  for (int o = 128; o > 0; o >>= 1) {
    if (tid < o) red[tid] += red[tid + o];
    __syncthreads();
  }
  float inv = 1.0f / red[0];
  __syncthreads();
  int j = tid & 127, half = tid >> 7;
  float acc = 0.0f;
  for (int i = lo + half; i < hi; i += 2)
    acc += gate[i] * bf2f(h[(size_t)i * 128 + j]);
  red[tid] = acc;
  __syncthreads();
  if (tid < 128) pooled[(size_t)g * 128 + tid] = (red[tid] + red[tid + 128]) * inv;
}

// ---------- classifier ----------
__global__ __launch_bounds__(128) void classifier(
    const float* __restrict__ pooled, const float* __restrict__ w1,
    const float* __restrict__ b1, const float* __restrict__ w2,
    const float* __restrict__ b2, float* __restrict__ out) {
  int g = blockIdx.x, j = threadIdx.x;
  __shared__ float p[128];
  __shared__ float r[128];
  p[j] = pooled[(size_t)g * 128 + j];
  __syncthreads();
  float acc = 0.0f;
#pragma unroll 8
  for (int k = 0; k < 128; ++k) acc = fmaf(p[k], w1[k * 128 + j], acc);
  acc += b1[j];
  r[j] = fmaxf(acc, 0.0f);
  __syncthreads();
  if (j < 2) {
    float a = 0.0f;
    for (int k = 0; k < 128; ++k) a = fmaf(r[k], w2[k * 2 + j], a);
    out[g * 2 + j] = a + b2[j];
  }
}

static inline size_t alup(size_t x) { return (x + 255) & ~(size_t)255; }

extern "C" void kernel_launch(void* const* d_in, const int* in_sizes, int n_in,
                              void* d_out, int out_size, void* d_ws, size_t ws_size,
                              hipStream_t stream) {
  const float* x    = (const float*)d_in[0];
  const int*   ei   = (const int*)d_in[1];
  const int*   bat  = (const int*)d_in[2];
  const float* W1   = (const float*)d_in[3];
  const float* b1   = (const float*)d_in[4];
  const float* ln1g = (const float*)d_in[5];
  const float* ln1b = (const float*)d_in[6];
  const float* W2   = (const float*)d_in[7];
  const float* b2   = (const float*)d_in[8];
  const float* ln2g = (const float*)d_in[9];
  const float* ln2b = (const float*)d_in[10];
  const float* gw1  = (const float*)d_in[11];
  const float* gb1  = (const float*)d_in[12];
  const float* gw2  = (const float*)d_in[13];
  const float* gb2  = (const float*)d_in[14];
  const float* cw1  = (const float*)d_in[15];
  const float* cb1  = (const float*)d_in[16];
  const float* cw2  = (const float*)d_in[17];
  const float* cb2  = (const float*)d_in[18];

  const int N = in_sizes[2];
  const int E = in_sizes[1] / 2;
  const int G = out_size / 2;
  const int* src = ei;
  const int* dst = ei + E;

  int nb256 = (N + 255) / 256;
  int eb256 = (E + 255) / 256;
  int mfmaB = (N + 127) / 128;
  int waveB_N = (N + 3) / 4;

  char* base = (char*)d_ws;
  unsigned int* deg = (unsigned int*)base; base += alup((size_t)N * 4);
  float* dinv = (float*)base;              base += alup((size_t)N * 4);
  int* offs = (int*)base;                  base += alup((size_t)(N + 1) * 4);
  int* cursor = (int*)base;                base += alup((size_t)N * 4);
  int* partial = (int*)base;               base += alup((size_t)nb256 * 4);
  int* col = (int*)base;                   base += alup((size_t)E * 4);
  unsigned short* pW1 = (unsigned short*)base; base += alup(32768 * 2);
  unsigned short* pW2 = (unsigned short*)base; base += alup(32768 * 2);
  unsigned short* pG1 = (unsigned short*)base; base += alup(32768 * 2);
  unsigned short* hbuf = (unsigned short*)base; base += alup((size_t)N * 128 * 2);
  unsigned short* hout = (unsigned short*)base; base += alup((size_t)N * 128 * 2);
  float* gate = (float*)base;              base += alup((size_t)N * 4);
  float* pooled = (float*)base;            base += alup((size_t)G * 128 * 4);

  float* out = (float*)d_out;

  // ---- degree -> dinv, CSR build, weight pack ----
  init_deg_u32<<<nb256, 256, 0, stream>>>(deg, N);
  accum_deg<<<eb256, 256, 0, stream>>>(dst, deg, E);
  finish_dinv<<<nb256, 256, 0, stream>>>(deg, dinv, N);
  scanA<<<nb256, 256, 0, stream>>>(deg, offs, partial, N);
  scanB<<<1, 64, 0, stream>>>(partial, nb256);
  scanC<<<nb256, 256, 0, stream>>>(offs, partial, cursor, N, E);
  scatter_csr<<<eb256, 256, 0, stream>>>(src, dst, cursor, col, E);
  pack_w<<<128, 256, 0, stream>>>(W1, pW1);
  pack_w<<<128, 256, 0, stream>>>(W2, pW2);
  pack_w<<<128, 256, 0, stream>>>(gw1, pG1);

  // ---- layer 1 ----
  gemm_f32in<<<mfmaB, 256, 0, stream>>>(x, pW1, hbuf, N);
  gather_ln<<<waveB_N, 256, 0, stream>>>(offs, col, dinv, hbuf, b1, ln1g, ln1b, hout, N);

  // ---- layer 2 ----
  gemm_b16in<<<mfmaB, 256, 0, stream>>>(hout, pW2, hbuf, N);
  gather_ln<<<waveB_N, 256, 0, stream>>>(offs, col, dinv, hbuf, b2, ln2g, ln2b, hout, N);

  // ---- gate MLP (fused) ----
  gemm_gate<<<mfmaB, 256, 0, stream>>>(hout, pG1, gb1, gw2, gb2, gate, N);

  // ---- attention pooling ----
  pool_kernel<<<G, 256, 0, stream>>>(gate, hout, bat, pooled, N);

  // ---- classifier ----
  classifier<<<G, 128, 0, stream>>>(pooled, cw1, cb1, cw2, cb2, out);
}

// Round 8
// 327.644 us; speedup vs baseline: 4.5911x; 1.1106x over previous
//
#include <hip/hip_runtime.h>
#include <hip/hip_bf16.h>

typedef short s8v __attribute__((ext_vector_type(8)));
typedef float f4v __attribute__((ext_vector_type(4)));

// ---------- bf16 helpers ----------
__device__ __forceinline__ unsigned short f2bf(float f) {  // RNE
  unsigned int u = __builtin_bit_cast(unsigned int, f);
  unsigned int r = u + 0x7fffu + ((u >> 16) & 1u);
  return (unsigned short)(r >> 16);
}
__device__ __forceinline__ float bf2f(unsigned short s) {
  return __builtin_bit_cast(float, ((unsigned int)s) << 16);
}
__device__ __forceinline__ float bflo(unsigned int v) {
  return __builtin_bit_cast(float, (unsigned int)(v << 16));
}
__device__ __forceinline__ float bfhi(unsigned int v) {
  return __builtin_bit_cast(float, (unsigned int)(v & 0xffff0000u));
}
__device__ __forceinline__ unsigned int packbf(float a, float b) {
  return (unsigned int)f2bf(a) | ((unsigned int)f2bf(b) << 16);
}

__device__ __forceinline__ int lower_bound_i(const int* a, int n, int key) {
  int lo = 0, hi = n;
  while (lo < hi) { int mid = (lo + hi) >> 1; if (a[mid] < key) lo = mid + 1; else hi = mid; }
  return lo;
}

// ---------- degree / dinv ----------
__global__ void init_deg_u32(unsigned int* deg, int n) {
  int i = blockIdx.x * blockDim.x + threadIdx.x;
  if (i < n) deg[i] = 1u;
}

__global__ void accum_deg(const int* __restrict__ dst, unsigned int* __restrict__ deg, int E) {
  int e = blockIdx.x * blockDim.x + threadIdx.x;
  if (e < E) atomicAdd(&deg[dst[e]], 1u);
}

// ---------- CSR build (scanA also emits dinv) ----------
__global__ __launch_bounds__(256) void scanA(const unsigned int* __restrict__ deg,
                                             int* __restrict__ offs, int* __restrict__ partial,
                                             float* __restrict__ dinv, int n) {
  __shared__ int sh[256];
  int t = threadIdx.x;
  int i = blockIdx.x * 256 + t;
  int v = (i < n) ? ((int)deg[i] - 1) : 0;
  if (i < n) dinv[i] = rsqrtf((float)deg[i]);
  sh[t] = v;
  __syncthreads();
  for (int o = 1; o < 256; o <<= 1) {
    int add = (t >= o) ? sh[t - o] : 0;
    __syncthreads();
    sh[t] += add;
    __syncthreads();
  }
  if (i < n) offs[i] = sh[t] - v;
  if (t == 255) partial[blockIdx.x] = sh[255];
}

__global__ void scanB(int* partial, int nb) {
  if (threadIdx.x == 0 && blockIdx.x == 0) {
    int run = 0;
    for (int j = 0; j < nb; ++j) { int v = partial[j]; partial[j] = run; run += v; }
  }
}

__global__ __launch_bounds__(256) void scanC(int* __restrict__ offs, const int* __restrict__ partial,
                                             int* __restrict__ cursor, int n, int E) {
  int i = blockIdx.x * 256 + threadIdx.x;
  if (i < n) {
    int o = offs[i] + partial[i >> 8];
    offs[i] = o;
    cursor[i] = o;
  }
  if (i == 0) offs[n] = E;
}

__global__ __launch_bounds__(256) void scatter_csr(const int* __restrict__ src, const int* __restrict__ dst,
                                                   int* __restrict__ cursor, int* __restrict__ col, int E) {
  int e = blockIdx.x * 256 + threadIdx.x;
  if (e < E) {
    int slot = atomicAdd(&cursor[dst[e]], 1);
    col[slot] = src[e];
  }
}

// ---------- weight pack: 3x fp32 [128x128] -> fragment-ordered split-bf16 ----------
__global__ __launch_bounds__(256) void pack_w3(const float* __restrict__ Wa, const float* __restrict__ Wb,
                                               const float* __restrict__ Wc, unsigned short* __restrict__ P) {
  int gidx = blockIdx.x * 256 + threadIdx.x;
  if (gidx >= 3 * 32768) return;
  int which = gidx >> 15;
  int idx = gidx & 32767;
  const float* W = (which == 0) ? Wa : (which == 1) ? Wb : Wc;
  int j = idx & 15;
  int lane = (idx >> 4) & 63;
  int t = (idx >> 10) & 7;
  int c = (idx >> 13) & 3;
  int k = c * 32 + (lane >> 4) * 8 + (j & 7);
  int n = t * 16 + (lane & 15);
  float f = W[k * 128 + n];
  unsigned short hi = f2bf(f);
  unsigned short outv = (j < 8) ? hi : f2bf(f - bf2f(hi));
  P[gidx] = outv;
}

// ---------- L1 GEMM: fp32 in (split-A, 3 MFMA), bf16 out; 64 rows/block ----------
__global__ __launch_bounds__(256) void gemm_f32in(
    const float* __restrict__ in, const unsigned short* __restrict__ P,
    unsigned short* __restrict__ out, int n) {
  __shared__ unsigned short wlds[32768];
  int tid = threadIdx.x;
  for (int i = tid; i < 4096; i += 256)
    reinterpret_cast<uint4*>(wlds)[i] = reinterpret_cast<const uint4*>(P)[i];
  __syncthreads();

  int wave = tid >> 6, lane = tid & 63;
  int quad = lane >> 4, col = lane & 15;
  int base = blockIdx.x * 64 + wave * 16;
  int m = base + col;

  f4v acc[8];
#pragma unroll
  for (int t = 0; t < 8; ++t) acc[t] = (f4v){0.f, 0.f, 0.f, 0.f};

  for (int c = 0; c < 4; ++c) {
    s8v ah, al;
    float v[8];
    if (m < n) {
      const float4* xp = reinterpret_cast<const float4*>(in + (size_t)m * 128 + c * 32 + quad * 8);
      float4 v0 = xp[0], v1 = xp[1];
      v[0] = v0.x; v[1] = v0.y; v[2] = v0.z; v[3] = v0.w;
      v[4] = v1.x; v[5] = v1.y; v[6] = v1.z; v[7] = v1.w;
    } else {
#pragma unroll
      for (int j = 0; j < 8; ++j) v[j] = 0.f;
    }
#pragma unroll
    for (int j = 0; j < 8; ++j) {
      unsigned short h = f2bf(v[j]);
      ah[j] = (short)h;
      al[j] = (short)f2bf(v[j] - bf2f(h));
    }
#pragma unroll
    for (int t = 0; t < 8; ++t) {
      const s8v* bp = reinterpret_cast<const s8v*>(&wlds[((c * 8 + t) * 64 + lane) * 16]);
      s8v bh = bp[0], bl = bp[1];
      acc[t] = __builtin_amdgcn_mfma_f32_16x16x32_bf16(ah, bh, acc[t], 0, 0, 0);
      acc[t] = __builtin_amdgcn_mfma_f32_16x16x32_bf16(ah, bl, acc[t], 0, 0, 0);
      acc[t] = __builtin_amdgcn_mfma_f32_16x16x32_bf16(al, bh, acc[t], 0, 0, 0);
    }
  }
#pragma unroll
  for (int t = 0; t < 8; ++t)
#pragma unroll
    for (int r = 0; r < 4; ++r) {
      int mm = base + quad * 4 + r;
      if (mm < n) out[(size_t)mm * 128 + t * 16 + col] = f2bf(acc[t][r]);
    }
}

// ---------- bf16-in GEMM (A direct, 2 MFMA), bf16 out; 64 rows/block ----------
__global__ __launch_bounds__(256) void gemm_b16in(
    const unsigned short* __restrict__ in, const unsigned short* __restrict__ P,
    unsigned short* __restrict__ out, int n) {
  __shared__ unsigned short wlds[32768];
  int tid = threadIdx.x;
  for (int i = tid; i < 4096; i += 256)
    reinterpret_cast<uint4*>(wlds)[i] = reinterpret_cast<const uint4*>(P)[i];
  __syncthreads();

  int wave = tid >> 6, lane = tid & 63;
  int quad = lane >> 4, col = lane & 15;
  int base = blockIdx.x * 64 + wave * 16;
  int m = base + col;

  f4v acc[8];
#pragma unroll
  for (int t = 0; t < 8; ++t) acc[t] = (f4v){0.f, 0.f, 0.f, 0.f};

  for (int c = 0; c < 4; ++c) {
    s8v ah;
    if (m < n)
      ah = *reinterpret_cast<const s8v*>(in + (size_t)m * 128 + c * 32 + quad * 8);
    else
      ah = (s8v){0, 0, 0, 0, 0, 0, 0, 0};
#pragma unroll
    for (int t = 0; t < 8; ++t) {
      const s8v* bp = reinterpret_cast<const s8v*>(&wlds[((c * 8 + t) * 64 + lane) * 16]);
      s8v bh = bp[0], bl = bp[1];
      acc[t] = __builtin_amdgcn_mfma_f32_16x16x32_bf16(ah, bh, acc[t], 0, 0, 0);
      acc[t] = __builtin_amdgcn_mfma_f32_16x16x32_bf16(ah, bl, acc[t], 0, 0, 0);
    }
  }
#pragma unroll
  for (int t = 0; t < 8; ++t)
#pragma unroll
    for (int r = 0; r < 4; ++r) {
      int mm = base + quad * 4 + r;
      if (mm < n) out[(size_t)mm * 128 + t * 16 + col] = f2bf(acc[t][r]);
    }
}

// ---------- gate GEMM: bf16 in, fused relu + dot(gw2) + reduce -> gate[N] fp32 ----------
__global__ __launch_bounds__(256) void gemm_gate(
    const unsigned short* __restrict__ in, const unsigned short* __restrict__ P,
    const float* __restrict__ gb1, const float* __restrict__ gw2,
    const float* __restrict__ gb2, float* __restrict__ gate, int n) {
  __shared__ unsigned short wlds[32768];
  int tid = threadIdx.x;
  for (int i = tid; i < 4096; i += 256)
    reinterpret_cast<uint4*>(wlds)[i] = reinterpret_cast<const uint4*>(P)[i];
  __syncthreads();

  int wave = tid >> 6, lane = tid & 63;
  int quad = lane >> 4, col = lane & 15;
  int base = blockIdx.x * 64 + wave * 16;
  int m = base + col;

  f4v acc[8];
#pragma unroll
  for (int t = 0; t < 8; ++t) acc[t] = (f4v){0.f, 0.f, 0.f, 0.f};

  for (int c = 0; c < 4; ++c) {
    s8v ah;
    if (m < n)
      ah = *reinterpret_cast<const s8v*>(in + (size_t)m * 128 + c * 32 + quad * 8);
    else
      ah = (s8v){0, 0, 0, 0, 0, 0, 0, 0};
#pragma unroll
    for (int t = 0; t < 8; ++t) {
      const s8v* bp = reinterpret_cast<const s8v*>(&wlds[((c * 8 + t) * 64 + lane) * 16]);
      s8v bh = bp[0], bl = bp[1];
      acc[t] = __builtin_amdgcn_mfma_f32_16x16x32_bf16(ah, bh, acc[t], 0, 0, 0);
      acc[t] = __builtin_amdgcn_mfma_f32_16x16x32_bf16(ah, bl, acc[t], 0, 0, 0);
    }
  }
  float bv[8], g2[8];
#pragma unroll
  for (int t = 0; t < 8; ++t) {
    bv[t] = gb1[t * 16 + col];
    g2[t] = gw2[t * 16 + col];
  }
  float gb2v = gb2[0];
#pragma unroll
  for (int r = 0; r < 4; ++r) {
    float p = 0.f;
#pragma unroll
    for (int t = 0; t < 8; ++t)
      p += fmaxf(acc[t][r] + bv[t], 0.f) * g2[t];
#pragma unroll
    for (int o = 1; o < 16; o <<= 1) p += __shfl_xor(p, o);
    int mm = base + quad * 4 + r;
    if (col == 0 && mm < n) gate[mm] = p + gb2v;
  }
}

// ---------- fused CSR gather + self-loop + bias + LayerNorm + ReLU (bf16 io) ----------
// 4 nodes per wave: 16 lanes/node, 8 features/lane (uint4 = 4 bf16-pairs)
__global__ __launch_bounds__(256) void gather_ln(
    const int* __restrict__ offs, const int* __restrict__ col,
    const float* __restrict__ dinv, const unsigned short* __restrict__ h,
    const float* __restrict__ bias, const float* __restrict__ gam,
    const float* __restrict__ bet, unsigned short* __restrict__ out, int n) {
  int wid = (int)((blockIdx.x * 256u + threadIdx.x) >> 6);
  int lane = threadIdx.x & 63;
  int grp = lane >> 4;   // node within wave
  int sub = lane & 15;   // 16 lanes per node
  int i = wid * 4 + grp;
  if (i >= n) return;
  const uint4* hu = reinterpret_cast<const uint4*>(h);  // row = 16 uint4
  float di = dinv[i];
  float sl = di * di;
  uint4 hv = hu[(size_t)i * 16 + sub];
  float4 b0v = reinterpret_cast<const float4*>(bias)[sub * 2];
  float4 b1v = reinterpret_cast<const float4*>(bias)[sub * 2 + 1];
  float v[8];
  v[0] = bflo(hv.x) * sl + b0v.x; v[1] = bfhi(hv.x) * sl + b0v.y;
  v[2] = bflo(hv.y) * sl + b0v.z; v[3] = bfhi(hv.y) * sl + b0v.w;
  v[4] = bflo(hv.z) * sl + b1v.x; v[5] = bfhi(hv.z) * sl + b1v.y;
  v[6] = bflo(hv.w) * sl + b1v.z; v[7] = bfhi(hv.w) * sl + b1v.w;
  int b0 = offs[i], b1 = offs[i + 1];
  int e = b0;
  for (; e + 2 <= b1; e += 2) {
    int s0 = col[e], s1 = col[e + 1];
    uint4 h0 = hu[(size_t)s0 * 16 + sub];
    uint4 h1 = hu[(size_t)s1 * 16 + sub];
    float n0 = dinv[s0] * di, n1 = dinv[s1] * di;
    v[0] += bflo(h0.x) * n0 + bflo(h1.x) * n1;
    v[1] += bfhi(h0.x) * n0 + bfhi(h1.x) * n1;
    v[2] += bflo(h0.y) * n0 + bflo(h1.y) * n1;
    v[3] += bfhi(h0.y) * n0 + bfhi(h1.y) * n1;
    v[4] += bflo(h0.z) * n0 + bflo(h1.z) * n1;
    v[5] += bfhi(h0.z) * n0 + bfhi(h1.z) * n1;
    v[6] += bflo(h0.w) * n0 + bflo(h1.w) * n1;
    v[7] += bfhi(h0.w) * n0 + bfhi(h1.w) * n1;
  }
  if (e < b1) {
    int s0 = col[e];
    uint4 h0 = hu[(size_t)s0 * 16 + sub];
    float n0 = dinv[s0] * di;
    v[0] += bflo(h0.x) * n0; v[1] += bfhi(h0.x) * n0;
    v[2] += bflo(h0.y) * n0; v[3] += bfhi(h0.y) * n0;
    v[4] += bflo(h0.z) * n0; v[5] += bfhi(h0.z) * n0;
    v[6] += bflo(h0.w) * n0; v[7] += bfhi(h0.w) * n0;
  }
  float s = 0.f, q = 0.f;
#pragma unroll
  for (int j = 0; j < 8; ++j) { s += v[j]; q += v[j] * v[j]; }
#pragma unroll
  for (int o = 1; o < 16; o <<= 1) {
    s += __shfl_xor(s, o);
    q += __shfl_xor(q, o);
  }
  float m = s * (1.0f / 128.0f);
  float var = q * (1.0f / 128.0f) - m * m;
  float rs = rsqrtf(var + 1e-5f);
  float4 g0 = reinterpret_cast<const float4*>(gam)[sub * 2];
  float4 g1 = reinterpret_cast<const float4*>(gam)[sub * 2 + 1];
  float4 e0 = reinterpret_cast<const float4*>(bet)[sub * 2];
  float4 e1 = reinterpret_cast<const float4*>(bet)[sub * 2 + 1];
  uint4 ov;
  ov.x = packbf(fmaxf((v[0] - m) * rs * g0.x + e0.x, 0.f), fmaxf((v[1] - m) * rs * g0.y + e0.y, 0.f));
  ov.y = packbf(fmaxf((v[2] - m) * rs * g0.z + e0.z, 0.f), fmaxf((v[3] - m) * rs * g0.w + e0.w, 0.f));
  ov.z = packbf(fmaxf((v[4] - m) * rs * g1.x + e1.x, 0.f), fmaxf((v[5] - m) * rs * g1.y + e1.y, 0.f));
  ov.w = packbf(fmaxf((v[6] - m) * rs * g1.z + e1.z, 0.f), fmaxf((v[7] - m) * rs * g1.w + e1.w, 0.f));
  reinterpret_cast<uint4*>(out)[(size_t)i * 16 + sub] = ov;
}

// ---------- attention pooling (bf16 h), 256 threads ----------
__global__ __launch_bounds__(256) void pool_kernel(
    float* __restrict__ gate, const unsigned short* __restrict__ h,
    const int* __restrict__ batch, float* __restrict__ pooled, int n) {
  int g = blockIdx.x;
  int tid = threadIdx.x;
  __shared__ float red[256];
  int lo = lower_bound_i(batch, n, g);
  int hi = lower_bound_i(batch, n, g + 1);
  if (lo >= hi) {
    if (tid < 128) pooled[(size_t)g * 128 + tid] = 0.0f;
    return;
  }
  float m = -3.0e38f;
  for (int i = lo + tid; i < hi; i += 256) m = fmaxf(m, gate[i]);
  red[tid] = m;
  __syncthreads();
#pragma unroll
  for (int o = 128; o > 0; o >>= 1) {
    if (tid < o) red[tid] = fmaxf(red[tid], red[tid + o]);
    __syncthreads();
  }
  m = red[0];
  __syncthreads();
  float s = 0.0f;
  for (int i = lo + tid; i < hi; i += 256) {
    float e = __expf(gate[i] - m);
    gate[i] = e;
    s += e;
  }
  red[tid] = s;
  __syncthreads();
#pragma unroll
  for (int o = 128; o > 0; o >>= 1) {
    if (tid < o) red[tid] += red[tid + o];
    __syncthreads();
  }
  float inv = 1.0f / red[0];
  __syncthreads();
  int j = tid & 127, half = tid >> 7;
  float acc = 0.0f;
  for (int i = lo + half; i < hi; i += 2)
    acc += gate[i] * bf2f(h[(size_t)i * 128 + j]);
  red[tid] = acc;
  __syncthreads();
  if (tid < 128) pooled[(size_t)g * 128 + tid] = (red[tid] + red[tid + 128]) * inv;
}

// ---------- classifier ----------
__global__ __launch_bounds__(128) void classifier(
    const float* __restrict__ pooled, const float* __restrict__ w1,
    const float* __restrict__ b1, const float* __restrict__ w2,
    const float* __restrict__ b2, float* __restrict__ out) {
  int g = blockIdx.x, j = threadIdx.x;
  __shared__ float p[128];
  __shared__ float r[128];
  p[j] = pooled[(size_t)g * 128 + j];
  __syncthreads();
  float acc = 0.0f;
#pragma unroll 8
  for (int k = 0; k < 128; ++k) acc = fmaf(p[k], w1[k * 128 + j], acc);
  acc += b1[j];
  r[j] = fmaxf(acc, 0.0f);
  __syncthreads();
  if (j < 2) {
    float a = 0.0f;
    for (int k = 0; k < 128; ++k) a = fmaf(r[k], w2[k * 2 + j], a);
    out[g * 2 + j] = a + b2[j];
  }
}

static inline size_t alup(size_t x) { return (x + 255) & ~(size_t)255; }

extern "C" void kernel_launch(void* const* d_in, const int* in_sizes, int n_in,
                              void* d_out, int out_size, void* d_ws, size_t ws_size,
                              hipStream_t stream) {
  const float* x    = (const float*)d_in[0];
  const int*   ei   = (const int*)d_in[1];
  const int*   bat  = (const int*)d_in[2];
  const float* W1   = (const float*)d_in[3];
  const float* b1   = (const float*)d_in[4];
  const float* ln1g = (const float*)d_in[5];
  const float* ln1b = (const float*)d_in[6];
  const float* W2   = (const float*)d_in[7];
  const float* b2   = (const float*)d_in[8];
  const float* ln2g = (const float*)d_in[9];
  const float* ln2b = (const float*)d_in[10];
  const float* gw1  = (const float*)d_in[11];
  const float* gb1  = (const float*)d_in[12];
  const float* gw2  = (const float*)d_in[13];
  const float* gb2  = (const float*)d_in[14];
  const float* cw1  = (const float*)d_in[15];
  const float* cb1  = (const float*)d_in[16];
  const float* cw2  = (const float*)d_in[17];
  const float* cb2  = (const float*)d_in[18];

  const int N = in_sizes[2];
  const int E = in_sizes[1] / 2;
  const int G = out_size / 2;
  const int* src = ei;
  const int* dst = ei + E;

  int nb256 = (N + 255) / 256;
  int eb256 = (E + 255) / 256;
  int mfmaB = (N + 63) / 64;
  int gatherB = (N + 15) / 16;  // 4 waves x 4 nodes per block

  char* base = (char*)d_ws;
  unsigned int* deg = (unsigned int*)base; base += alup((size_t)N * 4);
  float* dinv = (float*)base;              base += alup((size_t)N * 4);
  int* offs = (int*)base;                  base += alup((size_t)(N + 1) * 4);
  int* cursor = (int*)base;                base += alup((size_t)N * 4);
  int* partial = (int*)base;               base += alup((size_t)nb256 * 4);
  int* col = (int*)base;                   base += alup((size_t)E * 4);
  unsigned short* pW = (unsigned short*)base; base += alup((size_t)3 * 32768 * 2);
  unsigned short* hbuf = (unsigned short*)base; base += alup((size_t)N * 128 * 2);
  unsigned short* hout = (unsigned short*)base; base += alup((size_t)N * 128 * 2);
  float* gate = (float*)base;              base += alup((size_t)N * 4);
  float* pooled = (float*)base;            base += alup((size_t)G * 128 * 4);

  unsigned short* pW1 = pW;
  unsigned short* pW2 = pW + 32768;
  unsigned short* pG1 = pW + 65536;

  float* out = (float*)d_out;

  // ---- degree -> dinv, CSR build, weight pack ----
  init_deg_u32<<<nb256, 256, 0, stream>>>(deg, N);
  accum_deg<<<eb256, 256, 0, stream>>>(dst, deg, E);
  scanA<<<nb256, 256, 0, stream>>>(deg, offs, partial, dinv, N);
  scanB<<<1, 64, 0, stream>>>(partial, nb256);
  scanC<<<nb256, 256, 0, stream>>>(offs, partial, cursor, N, E);
  scatter_csr<<<eb256, 256, 0, stream>>>(src, dst, cursor, col, E);
  pack_w3<<<384, 256, 0, stream>>>(W1, W2, gw1, pW);

  // ---- layer 1 ----
  gemm_f32in<<<mfmaB, 256, 0, stream>>>(x, pW1, hbuf, N);
  gather_ln<<<gatherB, 256, 0, stream>>>(offs, col, dinv, hbuf, b1, ln1g, ln1b, hout, N);

  // ---- layer 2 ----
  gemm_b16in<<<mfmaB, 256, 0, stream>>>(hout, pW2, hbuf, N);
  gather_ln<<<gatherB, 256, 0, stream>>>(offs, col, dinv, hbuf, b2, ln2g, ln2b, hout, N);

  // ---- gate MLP (fused) ----
  gemm_gate<<<mfmaB, 256, 0, stream>>>(hout, pG1, gb1, gw2, gb2, gate, N);

  // ---- attention pooling ----
  pool_kernel<<<G, 256, 0, stream>>>(gate, hout, bat, pooled, N);

  // ---- classifier ----
  classifier<<<G, 128, 0, stream>>>(pooled, cw1, cb1, cw2, cb2, out);
}

// Round 9
// 289.708 us; speedup vs baseline: 5.1923x; 1.1309x over previous
//
#include <hip/hip_runtime.h>
#include <hip/hip_bf16.h>

typedef short s8v __attribute__((ext_vector_type(8)));
typedef float f4v __attribute__((ext_vector_type(4)));

// ---------- bf16 helpers ----------
__device__ __forceinline__ unsigned short f2bf(float f) {  // RNE
  unsigned int u = __builtin_bit_cast(unsigned int, f);
  unsigned int r = u + 0x7fffu + ((u >> 16) & 1u);
  return (unsigned short)(r >> 16);
}
__device__ __forceinline__ float bf2f(unsigned short s) {
  return __builtin_bit_cast(float, ((unsigned int)s) << 16);
}
__device__ __forceinline__ float bflo(unsigned int v) {
  return __builtin_bit_cast(float, (unsigned int)(v << 16));
}
__device__ __forceinline__ float bfhi(unsigned int v) {
  return __builtin_bit_cast(float, (unsigned int)(v & 0xffff0000u));
}
__device__ __forceinline__ unsigned int packbf(float a, float b) {
  return (unsigned int)f2bf(a) | ((unsigned int)f2bf(b) << 16);
}

__device__ __forceinline__ int lower_bound_i(const int* a, int n, int key) {
  int lo = 0, hi = n;
  while (lo < hi) { int mid = (lo + hi) >> 1; if (a[mid] < key) lo = mid + 1; else hi = mid; }
  return lo;
}

// ---------- degree ----------
__global__ void accum_deg(const int* __restrict__ dst, unsigned int* __restrict__ deg, int E) {
  int e = blockIdx.x * blockDim.x + threadIdx.x;
  if (e < E) atomicAdd(&deg[dst[e]], 1u);
}

// ---------- CSR build (deg = in-edge count, true degree = deg+1) ----------
__global__ __launch_bounds__(256) void scanA(const unsigned int* __restrict__ deg,
                                             int* __restrict__ offs, int* __restrict__ partial,
                                             float* __restrict__ dinv, int n) {
  __shared__ int sh[256];
  int t = threadIdx.x;
  int i = blockIdx.x * 256 + t;
  int v = (i < n) ? (int)deg[i] : 0;
  if (i < n) dinv[i] = rsqrtf((float)(deg[i] + 1u));
  sh[t] = v;
  __syncthreads();
  for (int o = 1; o < 256; o <<= 1) {
    int add = (t >= o) ? sh[t - o] : 0;
    __syncthreads();
    sh[t] += add;
    __syncthreads();
  }
  if (i < n) offs[i] = sh[t] - v;
  if (t == 255) partial[blockIdx.x] = sh[255];
}

// scanC with inlined cross-block prefix (removes serial scanB kernel)
__global__ __launch_bounds__(256) void scanC(int* __restrict__ offs, const int* __restrict__ partial,
                                             int* __restrict__ cursor, int n, int E) {
  __shared__ int red[256];
  int bid = blockIdx.x;
  int t = threadIdx.x;
  int s = 0;
  for (int j = t; j < bid; j += 256) s += partial[j];
  red[t] = s;
  __syncthreads();
#pragma unroll
  for (int o = 128; o > 0; o >>= 1) {
    if (t < o) red[t] += red[t + o];
    __syncthreads();
  }
  int pre = red[0];
  int i = bid * 256 + t;
  if (i < n) {
    int o = offs[i] + pre;
    offs[i] = o;
    cursor[i] = o;
  }
  if (i == 0) offs[n] = E;
}

__global__ __launch_bounds__(256) void scatter_csr(const int* __restrict__ src, const int* __restrict__ dst,
                                                   int* __restrict__ cursor, int* __restrict__ col, int E) {
  int e = blockIdx.x * 256 + threadIdx.x;
  if (e < E) {
    int slot = atomicAdd(&cursor[dst[e]], 1);
    col[slot] = src[e];
  }
}

// ---------- weight pack: 3x fp32 [128x128] -> fragment-ordered split-bf16 ----------
__global__ __launch_bounds__(256) void pack_w3(const float* __restrict__ Wa, const float* __restrict__ Wb,
                                               const float* __restrict__ Wc, unsigned short* __restrict__ P) {
  int gidx = blockIdx.x * 256 + threadIdx.x;
  if (gidx >= 3 * 32768) return;
  int which = gidx >> 15;
  int idx = gidx & 32767;
  const float* W = (which == 0) ? Wa : (which == 1) ? Wb : Wc;
  int j = idx & 15;
  int lane = (idx >> 4) & 63;
  int t = (idx >> 10) & 7;
  int c = (idx >> 13) & 3;
  int k = c * 32 + (lane >> 4) * 8 + (j & 7);
  int n = t * 16 + (lane & 15);
  float f = W[k * 128 + n];
  unsigned short hi = f2bf(f);
  unsigned short outv = (j < 8) ? hi : f2bf(f - bf2f(hi));
  P[gidx] = outv;
}

// ---------- L1 GEMM: fp32 in (split-A, 3 MFMA), bf16 out; 64 rows/block ----------
__global__ __launch_bounds__(256) void gemm_f32in(
    const float* __restrict__ in, const unsigned short* __restrict__ P,
    unsigned short* __restrict__ out, int n) {
  __shared__ unsigned short wlds[32768];
  int tid = threadIdx.x;
  for (int i = tid; i < 4096; i += 256)
    reinterpret_cast<uint4*>(wlds)[i] = reinterpret_cast<const uint4*>(P)[i];
  __syncthreads();

  int wave = tid >> 6, lane = tid & 63;
  int quad = lane >> 4, col = lane & 15;
  int base = blockIdx.x * 64 + wave * 16;
  int m = base + col;

  f4v acc[8];
#pragma unroll
  for (int t = 0; t < 8; ++t) acc[t] = (f4v){0.f, 0.f, 0.f, 0.f};

  for (int c = 0; c < 4; ++c) {
    s8v ah, al;
    float v[8];
    if (m < n) {
      const float4* xp = reinterpret_cast<const float4*>(in + (size_t)m * 128 + c * 32 + quad * 8);
      float4 v0 = xp[0], v1 = xp[1];
      v[0] = v0.x; v[1] = v0.y; v[2] = v0.z; v[3] = v0.w;
      v[4] = v1.x; v[5] = v1.y; v[6] = v1.z; v[7] = v1.w;
    } else {
#pragma unroll
      for (int j = 0; j < 8; ++j) v[j] = 0.f;
    }
#pragma unroll
    for (int j = 0; j < 8; ++j) {
      unsigned short h = f2bf(v[j]);
      ah[j] = (short)h;
      al[j] = (short)f2bf(v[j] - bf2f(h));
    }
#pragma unroll
    for (int t = 0; t < 8; ++t) {
      const s8v* bp = reinterpret_cast<const s8v*>(&wlds[((c * 8 + t) * 64 + lane) * 16]);
      s8v bh = bp[0], bl = bp[1];
      acc[t] = __builtin_amdgcn_mfma_f32_16x16x32_bf16(ah, bh, acc[t], 0, 0, 0);
      acc[t] = __builtin_amdgcn_mfma_f32_16x16x32_bf16(ah, bl, acc[t], 0, 0, 0);
      acc[t] = __builtin_amdgcn_mfma_f32_16x16x32_bf16(al, bh, acc[t], 0, 0, 0);
    }
  }
#pragma unroll
  for (int t = 0; t < 8; ++t)
#pragma unroll
    for (int r = 0; r < 4; ++r) {
      int mm = base + quad * 4 + r;
      if (mm < n) out[(size_t)mm * 128 + t * 16 + col] = f2bf(acc[t][r]);
    }
}

// ---------- bf16-in GEMM (A direct, 2 MFMA), bf16 out; 64 rows/block ----------
__global__ __launch_bounds__(256) void gemm_b16in(
    const unsigned short* __restrict__ in, const unsigned short* __restrict__ P,
    unsigned short* __restrict__ out, int n) {
  __shared__ unsigned short wlds[32768];
  int tid = threadIdx.x;
  for (int i = tid; i < 4096; i += 256)
    reinterpret_cast<uint4*>(wlds)[i] = reinterpret_cast<const uint4*>(P)[i];
  __syncthreads();

  int wave = tid >> 6, lane = tid & 63;
  int quad = lane >> 4, col = lane & 15;
  int base = blockIdx.x * 64 + wave * 16;
  int m = base + col;

  f4v acc[8];
#pragma unroll
  for (int t = 0; t < 8; ++t) acc[t] = (f4v){0.f, 0.f, 0.f, 0.f};

  for (int c = 0; c < 4; ++c) {
    s8v ah;
    if (m < n)
      ah = *reinterpret_cast<const s8v*>(in + (size_t)m * 128 + c * 32 + quad * 8);
    else
      ah = (s8v){0, 0, 0, 0, 0, 0, 0, 0};
#pragma unroll
    for (int t = 0; t < 8; ++t) {
      const s8v* bp = reinterpret_cast<const s8v*>(&wlds[((c * 8 + t) * 64 + lane) * 16]);
      s8v bh = bp[0], bl = bp[1];
      acc[t] = __builtin_amdgcn_mfma_f32_16x16x32_bf16(ah, bh, acc[t], 0, 0, 0);
      acc[t] = __builtin_amdgcn_mfma_f32_16x16x32_bf16(ah, bl, acc[t], 0, 0, 0);
    }
  }
#pragma unroll
  for (int t = 0; t < 8; ++t)
#pragma unroll
    for (int r = 0; r < 4; ++r) {
      int mm = base + quad * 4 + r;
      if (mm < n) out[(size_t)mm * 128 + t * 16 + col] = f2bf(acc[t][r]);
    }
}

// ---------- gate GEMM: bf16 in, fused relu + dot(gw2) + reduce -> gate[N] fp32 ----------
__global__ __launch_bounds__(256) void gemm_gate(
    const unsigned short* __restrict__ in, const unsigned short* __restrict__ P,
    const float* __restrict__ gb1, const float* __restrict__ gw2,
    const float* __restrict__ gb2, float* __restrict__ gate, int n) {
  __shared__ unsigned short wlds[32768];
  int tid = threadIdx.x;
  for (int i = tid; i < 4096; i += 256)
    reinterpret_cast<uint4*>(wlds)[i] = reinterpret_cast<const uint4*>(P)[i];
  __syncthreads();

  int wave = tid >> 6, lane = tid & 63;
  int quad = lane >> 4, col = lane & 15;
  int base = blockIdx.x * 64 + wave * 16;
  int m = base + col;

  f4v acc[8];
#pragma unroll
  for (int t = 0; t < 8; ++t) acc[t] = (f4v){0.f, 0.f, 0.f, 0.f};

  for (int c = 0; c < 4; ++c) {
    s8v ah;
    if (m < n)
      ah = *reinterpret_cast<const s8v*>(in + (size_t)m * 128 + c * 32 + quad * 8);
    else
      ah = (s8v){0, 0, 0, 0, 0, 0, 0, 0};
#pragma unroll
    for (int t = 0; t < 8; ++t) {
      const s8v* bp = reinterpret_cast<const s8v*>(&wlds[((c * 8 + t) * 64 + lane) * 16]);
      s8v bh = bp[0], bl = bp[1];
      acc[t] = __builtin_amdgcn_mfma_f32_16x16x32_bf16(ah, bh, acc[t], 0, 0, 0);
      acc[t] = __builtin_amdgcn_mfma_f32_16x16x32_bf16(ah, bl, acc[t], 0, 0, 0);
    }
  }
  float bv[8], g2[8];
#pragma unroll
  for (int t = 0; t < 8; ++t) {
    bv[t] = gb1[t * 16 + col];
    g2[t] = gw2[t * 16 + col];
  }
  float gb2v = gb2[0];
#pragma unroll
  for (int r = 0; r < 4; ++r) {
    float p = 0.f;
#pragma unroll
    for (int t = 0; t < 8; ++t)
      p += fmaxf(acc[t][r] + bv[t], 0.f) * g2[t];
#pragma unroll
    for (int o = 1; o < 16; o <<= 1) p += __shfl_xor(p, o);
    int mm = base + quad * 4 + r;
    if (col == 0 && mm < n) gate[mm] = p + gb2v;
  }
}

// ---------- fused CSR gather + self-loop + bias + LayerNorm + ReLU (bf16 io) ----------
// 4 nodes per wave: 16 lanes/node, 8 features/lane; neighbor loop unroll-4
__global__ __launch_bounds__(256) void gather_ln(
    const int* __restrict__ offs, const int* __restrict__ col,
    const float* __restrict__ dinv, const unsigned short* __restrict__ h,
    const float* __restrict__ bias, const float* __restrict__ gam,
    const float* __restrict__ bet, unsigned short* __restrict__ out, int n) {
  int wid = (int)((blockIdx.x * 256u + threadIdx.x) >> 6);
  int lane = threadIdx.x & 63;
  int grp = lane >> 4;
  int sub = lane & 15;
  int i = wid * 4 + grp;
  if (i >= n) return;
  const uint4* hu = reinterpret_cast<const uint4*>(h);
  float di = dinv[i];
  float sl = di * di;
  uint4 hv = hu[(size_t)i * 16 + sub];
  float4 b0v = reinterpret_cast<const float4*>(bias)[sub * 2];
  float4 b1v = reinterpret_cast<const float4*>(bias)[sub * 2 + 1];
  float v[8];
  v[0] = bflo(hv.x) * sl + b0v.x; v[1] = bfhi(hv.x) * sl + b0v.y;
  v[2] = bflo(hv.y) * sl + b0v.z; v[3] = bfhi(hv.y) * sl + b0v.w;
  v[4] = bflo(hv.z) * sl + b1v.x; v[5] = bfhi(hv.z) * sl + b1v.y;
  v[6] = bflo(hv.w) * sl + b1v.z; v[7] = bfhi(hv.w) * sl + b1v.w;
  int b0 = offs[i], b1 = offs[i + 1];
  int e = b0;
  for (; e + 4 <= b1; e += 4) {
    int s0 = col[e], s1 = col[e + 1], s2 = col[e + 2], s3 = col[e + 3];
    uint4 h0 = hu[(size_t)s0 * 16 + sub];
    uint4 h1 = hu[(size_t)s1 * 16 + sub];
    uint4 h2 = hu[(size_t)s2 * 16 + sub];
    uint4 h3 = hu[(size_t)s3 * 16 + sub];
    float n0 = dinv[s0] * di, n1 = dinv[s1] * di, n2 = dinv[s2] * di, n3 = dinv[s3] * di;
    v[0] += bflo(h0.x) * n0 + bflo(h1.x) * n1 + bflo(h2.x) * n2 + bflo(h3.x) * n3;
    v[1] += bfhi(h0.x) * n0 + bfhi(h1.x) * n1 + bfhi(h2.x) * n2 + bfhi(h3.x) * n3;
    v[2] += bflo(h0.y) * n0 + bflo(h1.y) * n1 + bflo(h2.y) * n2 + bflo(h3.y) * n3;
    v[3] += bfhi(h0.y) * n0 + bfhi(h1.y) * n1 + bfhi(h2.y) * n2 + bfhi(h3.y) * n3;
    v[4] += bflo(h0.z) * n0 + bflo(h1.z) * n1 + bflo(h2.z) * n2 + bflo(h3.z) * n3;
    v[5] += bfhi(h0.z) * n0 + bfhi(h1.z) * n1 + bfhi(h2.z) * n2 + bfhi(h3.z) * n3;
    v[6] += bflo(h0.w) * n0 + bflo(h1.w) * n1 + bflo(h2.w) * n2 + bflo(h3.w) * n3;
    v[7] += bfhi(h0.w) * n0 + bfhi(h1.w) * n1 + bfhi(h2.w) * n2 + bfhi(h3.w) * n3;
  }
  for (; e + 2 <= b1; e += 2) {
    int s0 = col[e], s1 = col[e + 1];
    uint4 h0 = hu[(size_t)s0 * 16 + sub];
    uint4 h1 = hu[(size_t)s1 * 16 + sub];
    float n0 = dinv[s0] * di, n1 = dinv[s1] * di;
    v[0] += bflo(h0.x) * n0 + bflo(h1.x) * n1;
    v[1] += bfhi(h0.x) * n0 + bfhi(h1.x) * n1;
    v[2] += bflo(h0.y) * n0 + bflo(h1.y) * n1;
    v[3] += bfhi(h0.y) * n0 + bfhi(h1.y) * n1;
    v[4] += bflo(h0.z) * n0 + bflo(h1.z) * n1;
    v[5] += bfhi(h0.z) * n0 + bfhi(h1.z) * n1;
    v[6] += bflo(h0.w) * n0 + bflo(h1.w) * n1;
    v[7] += bfhi(h0.w) * n0 + bfhi(h1.w) * n1;
  }
  if (e < b1) {
    int s0 = col[e];
    uint4 h0 = hu[(size_t)s0 * 16 + sub];
    float n0 = dinv[s0] * di;
    v[0] += bflo(h0.x) * n0; v[1] += bfhi(h0.x) * n0;
    v[2] += bflo(h0.y) * n0; v[3] += bfhi(h0.y) * n0;
    v[4] += bflo(h0.z) * n0; v[5] += bfhi(h0.z) * n0;
    v[6] += bflo(h0.w) * n0; v[7] += bfhi(h0.w) * n0;
  }
  float s = 0.f, q = 0.f;
#pragma unroll
  for (int j = 0; j < 8; ++j) { s += v[j]; q += v[j] * v[j]; }
#pragma unroll
  for (int o = 1; o < 16; o <<= 1) {
    s += __shfl_xor(s, o);
    q += __shfl_xor(q, o);
  }
  float m = s * (1.0f / 128.0f);
  float var = q * (1.0f / 128.0f) - m * m;
  float rs = rsqrtf(var + 1e-5f);
  float4 g0 = reinterpret_cast<const float4*>(gam)[sub * 2];
  float4 g1 = reinterpret_cast<const float4*>(gam)[sub * 2 + 1];
  float4 e0 = reinterpret_cast<const float4*>(bet)[sub * 2];
  float4 e1 = reinterpret_cast<const float4*>(bet)[sub * 2 + 1];
  uint4 ov;
  ov.x = packbf(fmaxf((v[0] - m) * rs * g0.x + e0.x, 0.f), fmaxf((v[1] - m) * rs * g0.y + e0.y, 0.f));
  ov.y = packbf(fmaxf((v[2] - m) * rs * g0.z + e0.z, 0.f), fmaxf((v[3] - m) * rs * g0.w + e0.w, 0.f));
  ov.z = packbf(fmaxf((v[4] - m) * rs * g1.x + e1.x, 0.f), fmaxf((v[5] - m) * rs * g1.y + e1.y, 0.f));
  ov.w = packbf(fmaxf((v[6] - m) * rs * g1.z + e1.z, 0.f), fmaxf((v[7] - m) * rs * g1.w + e1.w, 0.f));
  reinterpret_cast<uint4*>(out)[(size_t)i * 16 + sub] = ov;
}

// ---------- attention pooling (bf16 h), 256 threads, 4 row-groups x uint pairs ----------
__global__ __launch_bounds__(256) void pool_kernel(
    float* __restrict__ gate, const unsigned short* __restrict__ h,
    const int* __restrict__ batch, float* __restrict__ pooled, int n) {
  int g = blockIdx.x;
  int tid = threadIdx.x;
  __shared__ float red[256];
  __shared__ float red2[256];
  int lo = lower_bound_i(batch, n, g);
  int hi = lower_bound_i(batch, n, g + 1);
  if (lo >= hi) {
    if (tid < 128) pooled[(size_t)g * 128 + tid] = 0.0f;
    return;
  }
  float m = -3.0e38f;
  for (int i = lo + tid; i < hi; i += 256) m = fmaxf(m, gate[i]);
  red[tid] = m;
  __syncthreads();
#pragma unroll
  for (int o = 128; o > 0; o >>= 1) {
    if (tid < o) red[tid] = fmaxf(red[tid], red[tid + o]);
    __syncthreads();
  }
  m = red[0];
  __syncthreads();
  float s = 0.0f;
  for (int i = lo + tid; i < hi; i += 256) {
    float e = __expf(gate[i] - m);
    gate[i] = e;
    s += e;
  }
  red[tid] = s;
  __syncthreads();
#pragma unroll
  for (int o = 128; o > 0; o >>= 1) {
    if (tid < o) red[tid] += red[tid + o];
    __syncthreads();
  }
  float inv = 1.0f / red[0];
  __syncthreads();
  // weighted sum: lane j covers feature pair (2j,2j+1); 4 row-groups, unroll 2
  const unsigned int* hu = reinterpret_cast<const unsigned int*>(h);  // row = 64 uints
  int j = tid & 63, rgp = tid >> 6;  // 4 groups
  float a0 = 0.f, a1 = 0.f;
  int i = lo + rgp;
  for (; i + 4 < hi; i += 8) {
    unsigned int p0 = hu[(size_t)i * 64 + j];
    unsigned int p1 = hu[(size_t)(i + 4) * 64 + j];
    float w0 = gate[i], w1 = gate[i + 4];
    a0 += bflo(p0) * w0 + bflo(p1) * w1;
    a1 += bfhi(p0) * w0 + bfhi(p1) * w1;
  }
  if (i < hi) {
    unsigned int p0 = hu[(size_t)i * 64 + j];
    float w0 = gate[i];
    a0 += bflo(p0) * w0;
    a1 += bfhi(p0) * w0;
  }
  red[tid] = a0;
  red2[tid] = a1;
  __syncthreads();
  if (tid < 64) {
    float f0 = (red[tid] + red[tid + 64] + red[tid + 128] + red[tid + 192]) * inv;
    float f1 = (red2[tid] + red2[tid + 64] + red2[tid + 128] + red2[tid + 192]) * inv;
    reinterpret_cast<float2*>(pooled + (size_t)g * 128)[tid] = make_float2(f0, f1);
  }
}

// ---------- classifier ----------
__global__ __launch_bounds__(128) void classifier(
    const float* __restrict__ pooled, const float* __restrict__ w1,
    const float* __restrict__ b1, const float* __restrict__ w2,
    const float* __restrict__ b2, float* __restrict__ out) {
  int g = blockIdx.x, j = threadIdx.x;
  __shared__ float p[128];
  __shared__ float r[128];
  p[j] = pooled[(size_t)g * 128 + j];
  __syncthreads();
  float acc = 0.0f;
#pragma unroll 8
  for (int k = 0; k < 128; ++k) acc = fmaf(p[k], w1[k * 128 + j], acc);
  acc += b1[j];
  r[j] = fmaxf(acc, 0.0f);
  __syncthreads();
  if (j < 2) {
    float a = 0.0f;
    for (int k = 0; k < 128; ++k) a = fmaf(r[k], w2[k * 2 + j], a);
    out[g * 2 + j] = a + b2[j];
  }
}

static inline size_t alup(size_t x) { return (x + 255) & ~(size_t)255; }

extern "C" void kernel_launch(void* const* d_in, const int* in_sizes, int n_in,
                              void* d_out, int out_size, void* d_ws, size_t ws_size,
                              hipStream_t stream) {
  const float* x    = (const float*)d_in[0];
  const int*   ei   = (const int*)d_in[1];
  const int*   bat  = (const int*)d_in[2];
  const float* W1   = (const float*)d_in[3];
  const float* b1   = (const float*)d_in[4];
  const float* ln1g = (const float*)d_in[5];
  const float* ln1b = (const float*)d_in[6];
  const float* W2   = (const float*)d_in[7];
  const float* b2   = (const float*)d_in[8];
  const float* ln2g = (const float*)d_in[9];
  const float* ln2b = (const float*)d_in[10];
  const float* gw1  = (const float*)d_in[11];
  const float* gb1  = (const float*)d_in[12];
  const float* gw2  = (const float*)d_in[13];
  const float* gb2  = (const float*)d_in[14];
  const float* cw1  = (const float*)d_in[15];
  const float* cb1  = (const float*)d_in[16];
  const float* cw2  = (const float*)d_in[17];
  const float* cb2  = (const float*)d_in[18];

  const int N = in_sizes[2];
  const int E = in_sizes[1] / 2;
  const int G = out_size / 2;
  const int* src = ei;
  const int* dst = ei + E;

  int nb256 = (N + 255) / 256;
  int eb256 = (E + 255) / 256;
  int mfmaB = (N + 63) / 64;
  int gatherB = (N + 15) / 16;

  char* base = (char*)d_ws;
  unsigned int* deg = (unsigned int*)base; base += alup((size_t)N * 4);
  float* dinv = (float*)base;              base += alup((size_t)N * 4);
  int* offs = (int*)base;                  base += alup((size_t)(N + 1) * 4);
  int* cursor = (int*)base;                base += alup((size_t)N * 4);
  int* partial = (int*)base;               base += alup((size_t)nb256 * 4);
  int* col = (int*)base;                   base += alup((size_t)E * 4);
  unsigned short* pW = (unsigned short*)base; base += alup((size_t)3 * 32768 * 2);
  unsigned short* hbuf = (unsigned short*)base; base += alup((size_t)N * 128 * 2);
  unsigned short* hout = (unsigned short*)base; base += alup((size_t)N * 128 * 2);
  float* gate = (float*)base;              base += alup((size_t)N * 4);
  float* pooled = (float*)base;            base += alup((size_t)G * 128 * 4);

  unsigned short* pW1 = pW;
  unsigned short* pW2 = pW + 32768;
  unsigned short* pG1 = pW + 65536;

  float* out = (float*)d_out;

  // ---- degree -> dinv, CSR build, weight pack ----
  hipMemsetAsync(deg, 0, (size_t)N * 4, stream);
  accum_deg<<<eb256, 256, 0, stream>>>(dst, deg, E);
  scanA<<<nb256, 256, 0, stream>>>(deg, offs, partial, dinv, N);
  scanC<<<nb256, 256, 0, stream>>>(offs, partial, cursor, N, E);
  scatter_csr<<<eb256, 256, 0, stream>>>(src, dst, cursor, col, E);
  pack_w3<<<384, 256, 0, stream>>>(W1, W2, gw1, pW);

  // ---- layer 1 ----
  gemm_f32in<<<mfmaB, 256, 0, stream>>>(x, pW1, hbuf, N);
  gather_ln<<<gatherB, 256, 0, stream>>>(offs, col, dinv, hbuf, b1, ln1g, ln1b, hout, N);

  // ---- layer 2 ----
  gemm_b16in<<<mfmaB, 256, 0, stream>>>(hout, pW2, hbuf, N);
  gather_ln<<<gatherB, 256, 0, stream>>>(offs, col, dinv, hbuf, b2, ln2g, ln2b, hout, N);

  // ---- gate MLP (fused) ----
  gemm_gate<<<mfmaB, 256, 0, stream>>>(hout, pG1, gb1, gw2, gb2, gate, N);

  // ---- attention pooling ----
  pool_kernel<<<G, 256, 0, stream>>>(gate, hout, bat, pooled, N);

  // ---- classifier ----
  classifier<<<G, 128, 0, stream>>>(pooled, cw1, cb1, cw2, cb2, out);
}

// Round 10
// 281.519 us; speedup vs baseline: 5.3433x; 1.0291x over previous
//
#include <hip/hip_runtime.h>
#include <hip/hip_bf16.h>

typedef short s8v __attribute__((ext_vector_type(8)));
typedef float f4v __attribute__((ext_vector_type(4)));

// ---------- bf16 helpers ----------
__device__ __forceinline__ unsigned short f2bf(float f) {  // RNE
  unsigned int u = __builtin_bit_cast(unsigned int, f);
  unsigned int r = u + 0x7fffu + ((u >> 16) & 1u);
  return (unsigned short)(r >> 16);
}
__device__ __forceinline__ float bf2f(unsigned short s) {
  return __builtin_bit_cast(float, ((unsigned int)s) << 16);
}
__device__ __forceinline__ float bflo(unsigned int v) {
  return __builtin_bit_cast(float, (unsigned int)(v << 16));
}
__device__ __forceinline__ float bfhi(unsigned int v) {
  return __builtin_bit_cast(float, (unsigned int)(v & 0xffff0000u));
}
__device__ __forceinline__ unsigned int packbf(float a, float b) {
  return (unsigned int)f2bf(a) | ((unsigned int)f2bf(b) << 16);
}

__device__ __forceinline__ int lower_bound_i(const int* a, int n, int key) {
  int lo = 0, hi = n;
  while (lo < hi) { int mid = (lo + hi) >> 1; if (a[mid] < key) lo = mid + 1; else hi = mid; }
  return lo;
}

// ---------- K1: weight pack (3x) + deg zeroing, one dispatch ----------
// blocks [0,384): pack 3*32768 elements; blocks [384,...): zero deg
__global__ __launch_bounds__(256) void pack_zero(
    const float* __restrict__ Wa, const float* __restrict__ Wb, const float* __restrict__ Wc,
    unsigned short* __restrict__ P, unsigned int* __restrict__ deg, int n) {
  int bid = blockIdx.x;
  if (bid >= 384) {
    int i = (bid - 384) * 256 + threadIdx.x;
    if (i < n) deg[i] = 0u;
    return;
  }
  int gidx = bid * 256 + threadIdx.x;
  int which = gidx >> 15;
  int idx = gidx & 32767;
  const float* W = (which == 0) ? Wa : (which == 1) ? Wb : Wc;
  int j = idx & 15;
  int lane = (idx >> 4) & 63;
  int t = (idx >> 10) & 7;
  int c = (idx >> 13) & 3;
  int k = c * 32 + (lane >> 4) * 8 + (j & 7);
  int nn = t * 16 + (lane & 15);
  float f = W[k * 128 + nn];
  unsigned short hi = f2bf(f);
  unsigned short outv = (j < 8) ? hi : f2bf(f - bf2f(hi));
  P[gidx] = outv;
}

// ---------- degree ----------
__global__ void accum_deg(const int* __restrict__ dst, unsigned int* __restrict__ deg, int E) {
  int e = blockIdx.x * blockDim.x + threadIdx.x;
  if (e < E) atomicAdd(&deg[dst[e]], 1u);
}

// ---------- CSR build (deg = in-edge count, true degree = deg+1) ----------
__global__ __launch_bounds__(256) void scanA(const unsigned int* __restrict__ deg,
                                             int* __restrict__ offs, int* __restrict__ partial,
                                             float* __restrict__ dinv, int n) {
  __shared__ int sh[256];
  int t = threadIdx.x;
  int i = blockIdx.x * 256 + t;
  int v = (i < n) ? (int)deg[i] : 0;
  if (i < n) dinv[i] = rsqrtf((float)(deg[i] + 1u));
  sh[t] = v;
  __syncthreads();
  for (int o = 1; o < 256; o <<= 1) {
    int add = (t >= o) ? sh[t - o] : 0;
    __syncthreads();
    sh[t] += add;
    __syncthreads();
  }
  if (i < n) offs[i] = sh[t] - v;
  if (t == 255) partial[blockIdx.x] = sh[255];
}

__global__ __launch_bounds__(256) void scanC(int* __restrict__ offs, const int* __restrict__ partial,
                                             int* __restrict__ cursor, int n, int E) {
  __shared__ int red[256];
  int bid = blockIdx.x;
  int t = threadIdx.x;
  int s = 0;
  for (int j = t; j < bid; j += 256) s += partial[j];
  red[t] = s;
  __syncthreads();
#pragma unroll
  for (int o = 128; o > 0; o >>= 1) {
    if (t < o) red[t] += red[t + o];
    __syncthreads();
  }
  int pre = red[0];
  int i = bid * 256 + t;
  if (i < n) {
    int o = offs[i] + pre;
    offs[i] = o;
    cursor[i] = o;
  }
  if (i == 0) offs[n] = E;
}

// ---------- K5: merged CSR scatter (writes {src, dinv[src]}) + layer-1 GEMM ----------
// blocks [0, gemmBlocks): fp32-in split-A MFMA GEMM; rest: scatter
__global__ __launch_bounds__(256) void gemm1_scatter(
    const float* __restrict__ in, const unsigned short* __restrict__ P,
    unsigned short* __restrict__ out, int n,
    const int* __restrict__ src, const int* __restrict__ dst,
    int* __restrict__ cursor, int2* __restrict__ col2,
    const float* __restrict__ dinv, int E, int gemmBlocks) {
  __shared__ unsigned short wlds[32768];
  if ((int)blockIdx.x >= gemmBlocks) {
    int e = ((int)blockIdx.x - gemmBlocks) * 256 + threadIdx.x;
    if (e < E) {
      int d = dst[e];
      int s = src[e];
      int slot = atomicAdd(&cursor[d], 1);
      col2[slot] = make_int2(s, __builtin_bit_cast(int, dinv[s]));
    }
    return;
  }
  int tid = threadIdx.x;
  for (int i = tid; i < 4096; i += 256)
    reinterpret_cast<uint4*>(wlds)[i] = reinterpret_cast<const uint4*>(P)[i];
  __syncthreads();

  int wave = tid >> 6, lane = tid & 63;
  int quad = lane >> 4, col = lane & 15;
  int base = blockIdx.x * 64 + wave * 16;
  int m = base + col;

  f4v acc[8];
#pragma unroll
  for (int t = 0; t < 8; ++t) acc[t] = (f4v){0.f, 0.f, 0.f, 0.f};

  for (int c = 0; c < 4; ++c) {
    s8v ah, al;
    float v[8];
    if (m < n) {
      const float4* xp = reinterpret_cast<const float4*>(in + (size_t)m * 128 + c * 32 + quad * 8);
      float4 v0 = xp[0], v1 = xp[1];
      v[0] = v0.x; v[1] = v0.y; v[2] = v0.z; v[3] = v0.w;
      v[4] = v1.x; v[5] = v1.y; v[6] = v1.z; v[7] = v1.w;
    } else {
#pragma unroll
      for (int j = 0; j < 8; ++j) v[j] = 0.f;
    }
#pragma unroll
    for (int j = 0; j < 8; ++j) {
      unsigned short h = f2bf(v[j]);
      ah[j] = (short)h;
      al[j] = (short)f2bf(v[j] - bf2f(h));
    }
#pragma unroll
    for (int t = 0; t < 8; ++t) {
      const s8v* bp = reinterpret_cast<const s8v*>(&wlds[((c * 8 + t) * 64 + lane) * 16]);
      s8v bh = bp[0], bl = bp[1];
      acc[t] = __builtin_amdgcn_mfma_f32_16x16x32_bf16(ah, bh, acc[t], 0, 0, 0);
      acc[t] = __builtin_amdgcn_mfma_f32_16x16x32_bf16(ah, bl, acc[t], 0, 0, 0);
      acc[t] = __builtin_amdgcn_mfma_f32_16x16x32_bf16(al, bh, acc[t], 0, 0, 0);
    }
  }
#pragma unroll
  for (int t = 0; t < 8; ++t)
#pragma unroll
    for (int r = 0; r < 4; ++r) {
      int mm = base + quad * 4 + r;
      if (mm < n) out[(size_t)mm * 128 + t * 16 + col] = f2bf(acc[t][r]);
    }
}

// ---------- bf16-in GEMM (A direct, 2 MFMA), bf16 out; 64 rows/block ----------
__global__ __launch_bounds__(256) void gemm_b16in(
    const unsigned short* __restrict__ in, const unsigned short* __restrict__ P,
    unsigned short* __restrict__ out, int n) {
  __shared__ unsigned short wlds[32768];
  int tid = threadIdx.x;
  for (int i = tid; i < 4096; i += 256)
    reinterpret_cast<uint4*>(wlds)[i] = reinterpret_cast<const uint4*>(P)[i];
  __syncthreads();

  int wave = tid >> 6, lane = tid & 63;
  int quad = lane >> 4, col = lane & 15;
  int base = blockIdx.x * 64 + wave * 16;
  int m = base + col;

  f4v acc[8];
#pragma unroll
  for (int t = 0; t < 8; ++t) acc[t] = (f4v){0.f, 0.f, 0.f, 0.f};

  for (int c = 0; c < 4; ++c) {
    s8v ah;
    if (m < n)
      ah = *reinterpret_cast<const s8v*>(in + (size_t)m * 128 + c * 32 + quad * 8);
    else
      ah = (s8v){0, 0, 0, 0, 0, 0, 0, 0};
#pragma unroll
    for (int t = 0; t < 8; ++t) {
      const s8v* bp = reinterpret_cast<const s8v*>(&wlds[((c * 8 + t) * 64 + lane) * 16]);
      s8v bh = bp[0], bl = bp[1];
      acc[t] = __builtin_amdgcn_mfma_f32_16x16x32_bf16(ah, bh, acc[t], 0, 0, 0);
      acc[t] = __builtin_amdgcn_mfma_f32_16x16x32_bf16(ah, bl, acc[t], 0, 0, 0);
    }
  }
#pragma unroll
  for (int t = 0; t < 8; ++t)
#pragma unroll
    for (int r = 0; r < 4; ++r) {
      int mm = base + quad * 4 + r;
      if (mm < n) out[(size_t)mm * 128 + t * 16 + col] = f2bf(acc[t][r]);
    }
}

// ---------- gate GEMM: bf16 in, fused relu + dot(gw2) + reduce -> gate[N] fp32 ----------
__global__ __launch_bounds__(256) void gemm_gate(
    const unsigned short* __restrict__ in, const unsigned short* __restrict__ P,
    const float* __restrict__ gb1, const float* __restrict__ gw2,
    const float* __restrict__ gb2, float* __restrict__ gate, int n) {
  __shared__ unsigned short wlds[32768];
  int tid = threadIdx.x;
  for (int i = tid; i < 4096; i += 256)
    reinterpret_cast<uint4*>(wlds)[i] = reinterpret_cast<const uint4*>(P)[i];
  __syncthreads();

  int wave = tid >> 6, lane = tid & 63;
  int quad = lane >> 4, col = lane & 15;
  int base = blockIdx.x * 64 + wave * 16;
  int m = base + col;

  f4v acc[8];
#pragma unroll
  for (int t = 0; t < 8; ++t) acc[t] = (f4v){0.f, 0.f, 0.f, 0.f};

  for (int c = 0; c < 4; ++c) {
    s8v ah;
    if (m < n)
      ah = *reinterpret_cast<const s8v*>(in + (size_t)m * 128 + c * 32 + quad * 8);
    else
      ah = (s8v){0, 0, 0, 0, 0, 0, 0, 0};
#pragma unroll
    for (int t = 0; t < 8; ++t) {
      const s8v* bp = reinterpret_cast<const s8v*>(&wlds[((c * 8 + t) * 64 + lane) * 16]);
      s8v bh = bp[0], bl = bp[1];
      acc[t] = __builtin_amdgcn_mfma_f32_16x16x32_bf16(ah, bh, acc[t], 0, 0, 0);
      acc[t] = __builtin_amdgcn_mfma_f32_16x16x32_bf16(ah, bl, acc[t], 0, 0, 0);
    }
  }
  float bv[8], g2[8];
#pragma unroll
  for (int t = 0; t < 8; ++t) {
    bv[t] = gb1[t * 16 + col];
    g2[t] = gw2[t * 16 + col];
  }
  float gb2v = gb2[0];
#pragma unroll
  for (int r = 0; r < 4; ++r) {
    float p = 0.f;
#pragma unroll
    for (int t = 0; t < 8; ++t)
      p += fmaxf(acc[t][r] + bv[t], 0.f) * g2[t];
#pragma unroll
    for (int o = 1; o < 16; o <<= 1) p += __shfl_xor(p, o);
    int mm = base + quad * 4 + r;
    if (col == 0 && mm < n) gate[mm] = p + gb2v;
  }
}

// ---------- fused CSR gather + self-loop + bias + LayerNorm + ReLU (bf16 io) ----------
// 4 nodes/wave, 16 lanes/node, 8 feats/lane; col2 = {src, dinv[src]} pairs
__global__ __launch_bounds__(256) void gather_ln(
    const int* __restrict__ offs, const int2* __restrict__ col2,
    const float* __restrict__ dinv, const unsigned short* __restrict__ h,
    const float* __restrict__ bias, const float* __restrict__ gam,
    const float* __restrict__ bet, unsigned short* __restrict__ out, int n) {
  int wid = (int)((blockIdx.x * 256u + threadIdx.x) >> 6);
  int lane = threadIdx.x & 63;
  int grp = lane >> 4;
  int sub = lane & 15;
  int i = wid * 4 + grp;
  if (i >= n) return;
  const uint4* hu = reinterpret_cast<const uint4*>(h);
  float di = dinv[i];
  float sl = di * di;
  uint4 hv = hu[(size_t)i * 16 + sub];
  float4 b0v = reinterpret_cast<const float4*>(bias)[sub * 2];
  float4 b1v = reinterpret_cast<const float4*>(bias)[sub * 2 + 1];
  float v[8];
  v[0] = bflo(hv.x) * sl + b0v.x; v[1] = bfhi(hv.x) * sl + b0v.y;
  v[2] = bflo(hv.y) * sl + b0v.z; v[3] = bfhi(hv.y) * sl + b0v.w;
  v[4] = bflo(hv.z) * sl + b1v.x; v[5] = bfhi(hv.z) * sl + b1v.y;
  v[6] = bflo(hv.w) * sl + b1v.z; v[7] = bfhi(hv.w) * sl + b1v.w;
  int b0 = offs[i], b1 = offs[i + 1];
  int e = b0;
  for (; e + 4 <= b1; e += 4) {
    int2 c0 = col2[e], c1 = col2[e + 1], c2 = col2[e + 2], c3 = col2[e + 3];
    uint4 h0 = hu[(size_t)c0.x * 16 + sub];
    uint4 h1 = hu[(size_t)c1.x * 16 + sub];
    uint4 h2 = hu[(size_t)c2.x * 16 + sub];
    uint4 h3 = hu[(size_t)c3.x * 16 + sub];
    float n0 = __builtin_bit_cast(float, c0.y) * di;
    float n1 = __builtin_bit_cast(float, c1.y) * di;
    float n2 = __builtin_bit_cast(float, c2.y) * di;
    float n3 = __builtin_bit_cast(float, c3.y) * di;
    v[0] += bflo(h0.x) * n0 + bflo(h1.x) * n1 + bflo(h2.x) * n2 + bflo(h3.x) * n3;
    v[1] += bfhi(h0.x) * n0 + bfhi(h1.x) * n1 + bfhi(h2.x) * n2 + bfhi(h3.x) * n3;
    v[2] += bflo(h0.y) * n0 + bflo(h1.y) * n1 + bflo(h2.y) * n2 + bflo(h3.y) * n3;
    v[3] += bfhi(h0.y) * n0 + bfhi(h1.y) * n1 + bfhi(h2.y) * n2 + bfhi(h3.y) * n3;
    v[4] += bflo(h0.z) * n0 + bflo(h1.z) * n1 + bflo(h2.z) * n2 + bflo(h3.z) * n3;
    v[5] += bfhi(h0.z) * n0 + bfhi(h1.z) * n1 + bfhi(h2.z) * n2 + bfhi(h3.z) * n3;
    v[6] += bflo(h0.w) * n0 + bflo(h1.w) * n1 + bflo(h2.w) * n2 + bflo(h3.w) * n3;
    v[7] += bfhi(h0.w) * n0 + bfhi(h1.w) * n1 + bfhi(h2.w) * n2 + bfhi(h3.w) * n3;
  }
  for (; e < b1; ++e) {
    int2 c0 = col2[e];
    uint4 h0 = hu[(size_t)c0.x * 16 + sub];
    float n0 = __builtin_bit_cast(float, c0.y) * di;
    v[0] += bflo(h0.x) * n0; v[1] += bfhi(h0.x) * n0;
    v[2] += bflo(h0.y) * n0; v[3] += bfhi(h0.y) * n0;
    v[4] += bflo(h0.z) * n0; v[5] += bfhi(h0.z) * n0;
    v[6] += bflo(h0.w) * n0; v[7] += bfhi(h0.w) * n0;
  }
  float s = 0.f, q = 0.f;
#pragma unroll
  for (int j = 0; j < 8; ++j) { s += v[j]; q += v[j] * v[j]; }
#pragma unroll
  for (int o = 1; o < 16; o <<= 1) {
    s += __shfl_xor(s, o);
    q += __shfl_xor(q, o);
  }
  float m = s * (1.0f / 128.0f);
  float var = q * (1.0f / 128.0f) - m * m;
  float rs = rsqrtf(var + 1e-5f);
  float4 g0 = reinterpret_cast<const float4*>(gam)[sub * 2];
  float4 g1 = reinterpret_cast<const float4*>(gam)[sub * 2 + 1];
  float4 e0 = reinterpret_cast<const float4*>(bet)[sub * 2];
  float4 e1 = reinterpret_cast<const float4*>(bet)[sub * 2 + 1];
  uint4 ov;
  ov.x = packbf(fmaxf((v[0] - m) * rs * g0.x + e0.x, 0.f), fmaxf((v[1] - m) * rs * g0.y + e0.y, 0.f));
  ov.y = packbf(fmaxf((v[2] - m) * rs * g0.z + e0.z, 0.f), fmaxf((v[3] - m) * rs * g0.w + e0.w, 0.f));
  ov.z = packbf(fmaxf((v[4] - m) * rs * g1.x + e1.x, 0.f), fmaxf((v[5] - m) * rs * g1.y + e1.y, 0.f));
  ov.w = packbf(fmaxf((v[6] - m) * rs * g1.z + e1.z, 0.f), fmaxf((v[7] - m) * rs * g1.w + e1.w, 0.f));
  reinterpret_cast<uint4*>(out)[(size_t)i * 16 + sub] = ov;
}

// ---------- attention pooling + classifier fused (one block per graph) ----------
__global__ __launch_bounds__(256) void pool_cls(
    float* __restrict__ gate, const unsigned short* __restrict__ h,
    const int* __restrict__ batch,
    const float* __restrict__ w1, const float* __restrict__ b1,
    const float* __restrict__ w2, const float* __restrict__ b2,
    float* __restrict__ out, int n) {
  int g = blockIdx.x;
  int tid = threadIdx.x;
  __shared__ float red[256];
  __shared__ float red2[256];
  __shared__ float p[128];
  __shared__ float r[128];
  int lo = lower_bound_i(batch, n, g);
  int hi = lower_bound_i(batch, n, g + 1);
  if (lo >= hi) {
    if (tid < 128) p[tid] = 0.0f;
  } else {
    float m = -3.0e38f;
    for (int i = lo + tid; i < hi; i += 256) m = fmaxf(m, gate[i]);
    red[tid] = m;
    __syncthreads();
#pragma unroll
    for (int o = 128; o > 0; o >>= 1) {
      if (tid < o) red[tid] = fmaxf(red[tid], red[tid + o]);
      __syncthreads();
    }
    m = red[0];
    __syncthreads();
    float s = 0.0f;
    for (int i = lo + tid; i < hi; i += 256) {
      float e = __expf(gate[i] - m);
      gate[i] = e;
      s += e;
    }
    red[tid] = s;
    __syncthreads();
#pragma unroll
    for (int o = 128; o > 0; o >>= 1) {
      if (tid < o) red[tid] += red[tid + o];
      __syncthreads();
    }
    float inv = 1.0f / red[0];
    __syncthreads();
    const unsigned int* hu = reinterpret_cast<const unsigned int*>(h);
    int j = tid & 63, rgp = tid >> 6;
    float a0 = 0.f, a1 = 0.f;
    int i = lo + rgp;
    for (; i + 4 < hi; i += 8) {
      unsigned int p0 = hu[(size_t)i * 64 + j];
      unsigned int p1 = hu[(size_t)(i + 4) * 64 + j];
      float w0 = gate[i], w1v = gate[i + 4];
      a0 += bflo(p0) * w0 + bflo(p1) * w1v;
      a1 += bfhi(p0) * w0 + bfhi(p1) * w1v;
    }
    if (i < hi) {
      unsigned int p0 = hu[(size_t)i * 64 + j];
      float w0 = gate[i];
      a0 += bflo(p0) * w0;
      a1 += bfhi(p0) * w0;
    }
    red[tid] = a0;
    red2[tid] = a1;
    __syncthreads();
    if (tid < 64) {
      p[2 * tid]     = (red[tid] + red[tid + 64] + red[tid + 128] + red[tid + 192]) * inv;
      p[2 * tid + 1] = (red2[tid] + red2[tid + 64] + red2[tid + 128] + red2[tid + 192]) * inv;
    }
  }
  __syncthreads();
  // classifier: r = relu(p @ w1 + b1); logits = r @ w2 + b2
  int j = tid & 127, half = tid >> 7;
  float acc = 0.0f;
#pragma unroll 8
  for (int k = half * 64; k < half * 64 + 64; ++k)
    acc = fmaf(p[k], w1[k * 128 + j], acc);
  red[tid] = acc;
  __syncthreads();
  if (tid < 128) r[tid] = fmaxf(red[tid] + red[tid + 128] + b1[tid], 0.0f);
  __syncthreads();
  if (tid < 2) {
    float a = 0.0f;
    for (int k = 0; k < 128; ++k) a = fmaf(r[k], w2[k * 2 + tid], a);
    out[g * 2 + tid] = a + b2[tid];
  }
}

static inline size_t alup(size_t x) { return (x + 255) & ~(size_t)255; }

extern "C" void kernel_launch(void* const* d_in, const int* in_sizes, int n_in,
                              void* d_out, int out_size, void* d_ws, size_t ws_size,
                              hipStream_t stream) {
  const float* x    = (const float*)d_in[0];
  const int*   ei   = (const int*)d_in[1];
  const int*   bat  = (const int*)d_in[2];
  const float* W1   = (const float*)d_in[3];
  const float* b1   = (const float*)d_in[4];
  const float* ln1g = (const float*)d_in[5];
  const float* ln1b = (const float*)d_in[6];
  const float* W2   = (const float*)d_in[7];
  const float* b2   = (const float*)d_in[8];
  const float* ln2g = (const float*)d_in[9];
  const float* ln2b = (const float*)d_in[10];
  const float* gw1  = (const float*)d_in[11];
  const float* gb1  = (const float*)d_in[12];
  const float* gw2  = (const float*)d_in[13];
  const float* gb2  = (const float*)d_in[14];
  const float* cw1  = (const float*)d_in[15];
  const float* cb1  = (const float*)d_in[16];
  const float* cw2  = (const float*)d_in[17];
  const float* cb2  = (const float*)d_in[18];

  const int N = in_sizes[2];
  const int E = in_sizes[1] / 2;
  const int G = out_size / 2;
  const int* src = ei;
  const int* dst = ei + E;

  int nb256 = (N + 255) / 256;
  int eb256 = (E + 255) / 256;
  int mfmaB = (N + 63) / 64;
  int gatherB = (N + 15) / 16;

  char* base = (char*)d_ws;
  unsigned int* deg = (unsigned int*)base; base += alup((size_t)N * 4);
  float* dinv = (float*)base;              base += alup((size_t)N * 4);
  int* offs = (int*)base;                  base += alup((size_t)(N + 1) * 4);
  int* cursor = (int*)base;                base += alup((size_t)N * 4);
  int* partial = (int*)base;               base += alup((size_t)nb256 * 4);
  int2* col2 = (int2*)base;                base += alup((size_t)E * 8);
  unsigned short* pW = (unsigned short*)base; base += alup((size_t)3 * 32768 * 2);
  unsigned short* hbuf = (unsigned short*)base; base += alup((size_t)N * 128 * 2);
  unsigned short* hout = (unsigned short*)base; base += alup((size_t)N * 128 * 2);
  float* gate = (float*)base;              base += alup((size_t)N * 4);

  unsigned short* pW1 = pW;
  unsigned short* pW2 = pW + 32768;
  unsigned short* pG1 = pW + 65536;

  float* out = (float*)d_out;

  // ---- K1: pack weights + zero deg ----
  pack_zero<<<384 + nb256, 256, 0, stream>>>(W1, W2, gw1, pW, deg, N);
  // ---- degree & scan ----
  accum_deg<<<eb256, 256, 0, stream>>>(dst, deg, E);
  scanA<<<nb256, 256, 0, stream>>>(deg, offs, partial, dinv, N);
  scanC<<<nb256, 256, 0, stream>>>(offs, partial, cursor, N, E);
  // ---- K5: scatter CSR (with dinv[src]) overlapped with layer-1 GEMM ----
  gemm1_scatter<<<mfmaB + eb256, 256, 0, stream>>>(x, pW1, hbuf, N,
                                                   src, dst, cursor, col2, dinv, E, mfmaB);
  // ---- layer 1 gather+LN ----
  gather_ln<<<gatherB, 256, 0, stream>>>(offs, col2, dinv, hbuf, b1, ln1g, ln1b, hout, N);
  // ---- layer 2 ----
  gemm_b16in<<<mfmaB, 256, 0, stream>>>(hout, pW2, hbuf, N);
  gather_ln<<<gatherB, 256, 0, stream>>>(offs, col2, dinv, hbuf, b2, ln2g, ln2b, hout, N);
  // ---- gate MLP (fused) ----
  gemm_gate<<<mfmaB, 256, 0, stream>>>(hout, pG1, gb1, gw2, gb2, gate, N);
  // ---- pooling + classifier ----
  pool_cls<<<G, 256, 0, stream>>>(gate, hout, bat, cw1, cb1, cw2, cb2, out, N);
}

// Round 11
// 272.465 us; speedup vs baseline: 5.5209x; 1.0332x over previous
//
#include <hip/hip_runtime.h>
#include <hip/hip_bf16.h>

typedef short s8v __attribute__((ext_vector_type(8)));
typedef float f4v __attribute__((ext_vector_type(4)));

// ---------- bf16 helpers ----------
__device__ __forceinline__ unsigned short f2bf(float f) {  // RNE
  unsigned int u = __builtin_bit_cast(unsigned int, f);
  unsigned int r = u + 0x7fffu + ((u >> 16) & 1u);
  return (unsigned short)(r >> 16);
}
__device__ __forceinline__ float bf2f(unsigned short s) {
  return __builtin_bit_cast(float, ((unsigned int)s) << 16);
}
__device__ __forceinline__ float bflo(unsigned int v) {
  return __builtin_bit_cast(float, (unsigned int)(v << 16));
}
__device__ __forceinline__ float bfhi(unsigned int v) {
  return __builtin_bit_cast(float, (unsigned int)(v & 0xffff0000u));
}
__device__ __forceinline__ unsigned int packbf(float a, float b) {
  return (unsigned int)f2bf(a) | ((unsigned int)f2bf(b) << 16);
}

__device__ __forceinline__ int lower_bound_i(const int* a, int n, int key) {
  int lo = 0, hi = n;
  while (lo < hi) { int mid = (lo + hi) >> 1; if (a[mid] < key) lo = mid + 1; else hi = mid; }
  return lo;
}

// ---------- K1: weight pack (3x) + deg zeroing, one dispatch ----------
__global__ __launch_bounds__(256) void pack_zero(
    const float* __restrict__ Wa, const float* __restrict__ Wb, const float* __restrict__ Wc,
    unsigned short* __restrict__ P, unsigned int* __restrict__ deg, int n) {
  int bid = blockIdx.x;
  if (bid >= 384) {
    int i = (bid - 384) * 256 + threadIdx.x;
    if (i < n) deg[i] = 0u;
    return;
  }
  int gidx = bid * 256 + threadIdx.x;
  int which = gidx >> 15;
  int idx = gidx & 32767;
  const float* W = (which == 0) ? Wa : (which == 1) ? Wb : Wc;
  int j = idx & 15;
  int lane = (idx >> 4) & 63;
  int t = (idx >> 10) & 7;
  int c = (idx >> 13) & 3;
  int k = c * 32 + (lane >> 4) * 8 + (j & 7);
  int nn = t * 16 + (lane & 15);
  float f = W[k * 128 + nn];
  unsigned short hi = f2bf(f);
  unsigned short outv = (j < 8) ? hi : f2bf(f - bf2f(hi));
  P[gidx] = outv;
}

// ---------- degree ----------
__global__ void accum_deg(const int* __restrict__ dst, unsigned int* __restrict__ deg, int E) {
  int e = blockIdx.x * blockDim.x + threadIdx.x;
  if (e < E) atomicAdd(&deg[dst[e]], 1u);
}

// ---------- CSR build ----------
__global__ __launch_bounds__(256) void scanA(const unsigned int* __restrict__ deg,
                                             int* __restrict__ offs, int* __restrict__ partial,
                                             float* __restrict__ dinv, int n) {
  __shared__ int sh[256];
  int t = threadIdx.x;
  int i = blockIdx.x * 256 + t;
  int v = (i < n) ? (int)deg[i] : 0;
  if (i < n) dinv[i] = rsqrtf((float)(deg[i] + 1u));
  sh[t] = v;
  __syncthreads();
  for (int o = 1; o < 256; o <<= 1) {
    int add = (t >= o) ? sh[t - o] : 0;
    __syncthreads();
    sh[t] += add;
    __syncthreads();
  }
  if (i < n) offs[i] = sh[t] - v;
  if (t == 255) partial[blockIdx.x] = sh[255];
}

__global__ __launch_bounds__(256) void scanC(int* __restrict__ offs, const int* __restrict__ partial,
                                             int* __restrict__ cursor, int n, int E) {
  __shared__ int red[256];
  int bid = blockIdx.x;
  int t = threadIdx.x;
  int s = 0;
  for (int j = t; j < bid; j += 256) s += partial[j];
  red[t] = s;
  __syncthreads();
#pragma unroll
  for (int o = 128; o > 0; o >>= 1) {
    if (t < o) red[t] += red[t + o];
    __syncthreads();
  }
  int pre = red[0];
  int i = bid * 256 + t;
  if (i < n) {
    int o = offs[i] + pre;
    offs[i] = o;
    cursor[i] = o;
  }
  if (i == 0) offs[n] = E;
}

// ---------- K5: merged CSR scatter + layer-1 GEMM (NO LDS — B read from L2) ----------
__global__ __launch_bounds__(256) void gemm1_scatter(
    const float* __restrict__ in, const unsigned short* __restrict__ P,
    unsigned short* __restrict__ out, int n,
    const int* __restrict__ src, const int* __restrict__ dst,
    int* __restrict__ cursor, int2* __restrict__ col2,
    const float* __restrict__ dinv, int E, int gemmBlocks) {
  if ((int)blockIdx.x >= gemmBlocks) {
    int e = ((int)blockIdx.x - gemmBlocks) * 256 + threadIdx.x;
    if (e < E) {
      int d = dst[e];
      int s = src[e];
      int slot = atomicAdd(&cursor[d], 1);
      col2[slot] = make_int2(s, __builtin_bit_cast(int, dinv[s]));
    }
    return;
  }
  int tid = threadIdx.x;
  int wave = tid >> 6, lane = tid & 63;
  int quad = lane >> 4, col = lane & 15;
  int base = blockIdx.x * 64 + wave * 16;
  int m = base + col;

  f4v acc[8];
#pragma unroll
  for (int t = 0; t < 8; ++t) acc[t] = (f4v){0.f, 0.f, 0.f, 0.f};

  for (int c = 0; c < 4; ++c) {
    s8v ah, al;
    float v[8];
    if (m < n) {
      const float4* xp = reinterpret_cast<const float4*>(in + (size_t)m * 128 + c * 32 + quad * 8);
      float4 v0 = xp[0], v1 = xp[1];
      v[0] = v0.x; v[1] = v0.y; v[2] = v0.z; v[3] = v0.w;
      v[4] = v1.x; v[5] = v1.y; v[6] = v1.z; v[7] = v1.w;
    } else {
#pragma unroll
      for (int j = 0; j < 8; ++j) v[j] = 0.f;
    }
#pragma unroll
    for (int j = 0; j < 8; ++j) {
      unsigned short h = f2bf(v[j]);
      ah[j] = (short)h;
      al[j] = (short)f2bf(v[j] - bf2f(h));
    }
#pragma unroll
    for (int t = 0; t < 8; ++t) {
      const s8v* bp = reinterpret_cast<const s8v*>(&P[((c * 8 + t) * 64 + lane) * 16]);
      s8v bh = bp[0], bl = bp[1];
      acc[t] = __builtin_amdgcn_mfma_f32_16x16x32_bf16(ah, bh, acc[t], 0, 0, 0);
      acc[t] = __builtin_amdgcn_mfma_f32_16x16x32_bf16(ah, bl, acc[t], 0, 0, 0);
      acc[t] = __builtin_amdgcn_mfma_f32_16x16x32_bf16(al, bh, acc[t], 0, 0, 0);
    }
  }
#pragma unroll
  for (int t = 0; t < 8; ++t)
#pragma unroll
    for (int r = 0; r < 4; ++r) {
      int mm = base + quad * 4 + r;
      if (mm < n) out[(size_t)mm * 128 + t * 16 + col] = f2bf(acc[t][r]);
    }
}

// ---------- bf16-in GEMM (A direct, 2 MFMA), bf16 out; NO LDS ----------
__global__ __launch_bounds__(256) void gemm_b16in(
    const unsigned short* __restrict__ in, const unsigned short* __restrict__ P,
    unsigned short* __restrict__ out, int n) {
  int tid = threadIdx.x;
  int wave = tid >> 6, lane = tid & 63;
  int quad = lane >> 4, col = lane & 15;
  int base = blockIdx.x * 64 + wave * 16;
  int m = base + col;

  f4v acc[8];
#pragma unroll
  for (int t = 0; t < 8; ++t) acc[t] = (f4v){0.f, 0.f, 0.f, 0.f};

  for (int c = 0; c < 4; ++c) {
    s8v ah;
    if (m < n)
      ah = *reinterpret_cast<const s8v*>(in + (size_t)m * 128 + c * 32 + quad * 8);
    else
      ah = (s8v){0, 0, 0, 0, 0, 0, 0, 0};
#pragma unroll
    for (int t = 0; t < 8; ++t) {
      const s8v* bp = reinterpret_cast<const s8v*>(&P[((c * 8 + t) * 64 + lane) * 16]);
      s8v bh = bp[0], bl = bp[1];
      acc[t] = __builtin_amdgcn_mfma_f32_16x16x32_bf16(ah, bh, acc[t], 0, 0, 0);
      acc[t] = __builtin_amdgcn_mfma_f32_16x16x32_bf16(ah, bl, acc[t], 0, 0, 0);
    }
  }
#pragma unroll
  for (int t = 0; t < 8; ++t)
#pragma unroll
    for (int r = 0; r < 4; ++r) {
      int mm = base + quad * 4 + r;
      if (mm < n) out[(size_t)mm * 128 + t * 16 + col] = f2bf(acc[t][r]);
    }
}

// ---------- gate GEMM: bf16 in, fused relu + dot(gw2) + reduce -> gate[N]; NO LDS ----------
__global__ __launch_bounds__(256) void gemm_gate(
    const unsigned short* __restrict__ in, const unsigned short* __restrict__ P,
    const float* __restrict__ gb1, const float* __restrict__ gw2,
    const float* __restrict__ gb2, float* __restrict__ gate, int n) {
  int tid = threadIdx.x;
  int wave = tid >> 6, lane = tid & 63;
  int quad = lane >> 4, col = lane & 15;
  int base = blockIdx.x * 64 + wave * 16;
  int m = base + col;

  f4v acc[8];
#pragma unroll
  for (int t = 0; t < 8; ++t) acc[t] = (f4v){0.f, 0.f, 0.f, 0.f};

  for (int c = 0; c < 4; ++c) {
    s8v ah;
    if (m < n)
      ah = *reinterpret_cast<const s8v*>(in + (size_t)m * 128 + c * 32 + quad * 8);
    else
      ah = (s8v){0, 0, 0, 0, 0, 0, 0, 0};
#pragma unroll
    for (int t = 0; t < 8; ++t) {
      const s8v* bp = reinterpret_cast<const s8v*>(&P[((c * 8 + t) * 64 + lane) * 16]);
      s8v bh = bp[0], bl = bp[1];
      acc[t] = __builtin_amdgcn_mfma_f32_16x16x32_bf16(ah, bh, acc[t], 0, 0, 0);
      acc[t] = __builtin_amdgcn_mfma_f32_16x16x32_bf16(ah, bl, acc[t], 0, 0, 0);
    }
  }
  float bv[8], g2[8];
#pragma unroll
  for (int t = 0; t < 8; ++t) {
    bv[t] = gb1[t * 16 + col];
    g2[t] = gw2[t * 16 + col];
  }
  float gb2v = gb2[0];
#pragma unroll
  for (int r = 0; r < 4; ++r) {
    float p = 0.f;
#pragma unroll
    for (int t = 0; t < 8; ++t)
      p += fmaxf(acc[t][r] + bv[t], 0.f) * g2[t];
#pragma unroll
    for (int o = 1; o < 16; o <<= 1) p += __shfl_xor(p, o);
    int mm = base + quad * 4 + r;
    if (col == 0 && mm < n) gate[mm] = p + gb2v;
  }
}

// ---------- fused CSR gather + self-loop + bias + LayerNorm + ReLU (bf16 io) ----------
__global__ __launch_bounds__(256) void gather_ln(
    const int* __restrict__ offs, const int2* __restrict__ col2,
    const float* __restrict__ dinv, const unsigned short* __restrict__ h,
    const float* __restrict__ bias, const float* __restrict__ gam,
    const float* __restrict__ bet, unsigned short* __restrict__ out, int n) {
  int wid = (int)((blockIdx.x * 256u + threadIdx.x) >> 6);
  int lane = threadIdx.x & 63;
  int grp = lane >> 4;
  int sub = lane & 15;
  int i = wid * 4 + grp;
  if (i >= n) return;
  const uint4* hu = reinterpret_cast<const uint4*>(h);
  float di = dinv[i];
  float sl = di * di;
  uint4 hv = hu[(size_t)i * 16 + sub];
  float4 b0v = reinterpret_cast<const float4*>(bias)[sub * 2];
  float4 b1v = reinterpret_cast<const float4*>(bias)[sub * 2 + 1];
  float v[8];
  v[0] = bflo(hv.x) * sl + b0v.x; v[1] = bfhi(hv.x) * sl + b0v.y;
  v[2] = bflo(hv.y) * sl + b0v.z; v[3] = bfhi(hv.y) * sl + b0v.w;
  v[4] = bflo(hv.z) * sl + b1v.x; v[5] = bfhi(hv.z) * sl + b1v.y;
  v[6] = bflo(hv.w) * sl + b1v.z; v[7] = bfhi(hv.w) * sl + b1v.w;
  int b0 = offs[i], b1 = offs[i + 1];
  int e = b0;
  for (; e + 4 <= b1; e += 4) {
    int2 c0 = col2[e], c1 = col2[e + 1], c2 = col2[e + 2], c3 = col2[e + 3];
    uint4 h0 = hu[(size_t)c0.x * 16 + sub];
    uint4 h1 = hu[(size_t)c1.x * 16 + sub];
    uint4 h2 = hu[(size_t)c2.x * 16 + sub];
    uint4 h3 = hu[(size_t)c3.x * 16 + sub];
    float n0 = __builtin_bit_cast(float, c0.y) * di;
    float n1 = __builtin_bit_cast(float, c1.y) * di;
    float n2 = __builtin_bit_cast(float, c2.y) * di;
    float n3 = __builtin_bit_cast(float, c3.y) * di;
    v[0] += bflo(h0.x) * n0 + bflo(h1.x) * n1 + bflo(h2.x) * n2 + bflo(h3.x) * n3;
    v[1] += bfhi(h0.x) * n0 + bfhi(h1.x) * n1 + bfhi(h2.x) * n2 + bfhi(h3.x) * n3;
    v[2] += bflo(h0.y) * n0 + bflo(h1.y) * n1 + bflo(h2.y) * n2 + bflo(h3.y) * n3;
    v[3] += bfhi(h0.y) * n0 + bfhi(h1.y) * n1 + bfhi(h2.y) * n2 + bfhi(h3.y) * n3;
    v[4] += bflo(h0.z) * n0 + bflo(h1.z) * n1 + bflo(h2.z) * n2 + bflo(h3.z) * n3;
    v[5] += bfhi(h0.z) * n0 + bfhi(h1.z) * n1 + bfhi(h2.z) * n2 + bfhi(h3.z) * n3;
    v[6] += bflo(h0.w) * n0 + bflo(h1.w) * n1 + bflo(h2.w) * n2 + bflo(h3.w) * n3;
    v[7] += bfhi(h0.w) * n0 + bfhi(h1.w) * n1 + bfhi(h2.w) * n2 + bfhi(h3.w) * n3;
  }
  for (; e < b1; ++e) {
    int2 c0 = col2[e];
    uint4 h0 = hu[(size_t)c0.x * 16 + sub];
    float n0 = __builtin_bit_cast(float, c0.y) * di;
    v[0] += bflo(h0.x) * n0; v[1] += bfhi(h0.x) * n0;
    v[2] += bflo(h0.y) * n0; v[3] += bfhi(h0.y) * n0;
    v[4] += bflo(h0.z) * n0; v[5] += bfhi(h0.z) * n0;
    v[6] += bflo(h0.w) * n0; v[7] += bfhi(h0.w) * n0;
  }
  float s = 0.f, q = 0.f;
#pragma unroll
  for (int j = 0; j < 8; ++j) { s += v[j]; q += v[j] * v[j]; }
#pragma unroll
  for (int o = 1; o < 16; o <<= 1) {
    s += __shfl_xor(s, o);
    q += __shfl_xor(q, o);
  }
  float m = s * (1.0f / 128.0f);
  float var = q * (1.0f / 128.0f) - m * m;
  float rs = rsqrtf(var + 1e-5f);
  float4 g0 = reinterpret_cast<const float4*>(gam)[sub * 2];
  float4 g1 = reinterpret_cast<const float4*>(gam)[sub * 2 + 1];
  float4 e0 = reinterpret_cast<const float4*>(bet)[sub * 2];
  float4 e1 = reinterpret_cast<const float4*>(bet)[sub * 2 + 1];
  uint4 ov;
  ov.x = packbf(fmaxf((v[0] - m) * rs * g0.x + e0.x, 0.f), fmaxf((v[1] - m) * rs * g0.y + e0.y, 0.f));
  ov.y = packbf(fmaxf((v[2] - m) * rs * g0.z + e0.z, 0.f), fmaxf((v[3] - m) * rs * g0.w + e0.w, 0.f));
  ov.z = packbf(fmaxf((v[4] - m) * rs * g1.x + e1.x, 0.f), fmaxf((v[5] - m) * rs * g1.y + e1.y, 0.f));
  ov.w = packbf(fmaxf((v[6] - m) * rs * g1.z + e1.z, 0.f), fmaxf((v[7] - m) * rs * g1.w + e1.w, 0.f));
  reinterpret_cast<uint4*>(out)[(size_t)i * 16 + sub] = ov;
}

// ---------- attention pooling + classifier fused (one block per graph) ----------
__global__ __launch_bounds__(256) void pool_cls(
    float* __restrict__ gate, const unsigned short* __restrict__ h,
    const int* __restrict__ batch,
    const float* __restrict__ w1, const float* __restrict__ b1,
    const float* __restrict__ w2, const float* __restrict__ b2,
    float* __restrict__ out, int n) {
  int g = blockIdx.x;
  int tid = threadIdx.x;
  __shared__ float red[256];
  __shared__ float red2[256];
  __shared__ float p[128];
  __shared__ float r[128];
  int lo = lower_bound_i(batch, n, g);
  int hi = lower_bound_i(batch, n, g + 1);
  if (lo >= hi) {
    if (tid < 128) p[tid] = 0.0f;
  } else {
    float m = -3.0e38f;
    for (int i = lo + tid; i < hi; i += 256) m = fmaxf(m, gate[i]);
    red[tid] = m;
    __syncthreads();
#pragma unroll
    for (int o = 128; o > 0; o >>= 1) {
      if (tid < o) red[tid] = fmaxf(red[tid], red[tid + o]);
      __syncthreads();
    }
    m = red[0];
    __syncthreads();
    float s = 0.0f;
    for (int i = lo + tid; i < hi; i += 256) {
      float e = __expf(gate[i] - m);
      gate[i] = e;
      s += e;
    }
    red[tid] = s;
    __syncthreads();
#pragma unroll
    for (int o = 128; o > 0; o >>= 1) {
      if (tid < o) red[tid] += red[tid + o];
      __syncthreads();
    }
    float inv = 1.0f / red[0];
    __syncthreads();
    const unsigned int* hu = reinterpret_cast<const unsigned int*>(h);
    int j = tid & 63, rgp = tid >> 6;
    float a0 = 0.f, a1 = 0.f;
    int i = lo + rgp;
    for (; i + 4 < hi; i += 8) {
      unsigned int p0 = hu[(size_t)i * 64 + j];
      unsigned int p1 = hu[(size_t)(i + 4) * 64 + j];
      float w0 = gate[i], w1v = gate[i + 4];
      a0 += bflo(p0) * w0 + bflo(p1) * w1v;
      a1 += bfhi(p0) * w0 + bfhi(p1) * w1v;
    }
    if (i < hi) {
      unsigned int p0 = hu[(size_t)i * 64 + j];
      float w0 = gate[i];
      a0 += bflo(p0) * w0;
      a1 += bfhi(p0) * w0;
    }
    red[tid] = a0;
    red2[tid] = a1;
    __syncthreads();
    if (tid < 64) {
      p[2 * tid]     = (red[tid] + red[tid + 64] + red[tid + 128] + red[tid + 192]) * inv;
      p[2 * tid + 1] = (red2[tid] + red2[tid + 64] + red2[tid + 128] + red2[tid + 192]) * inv;
    }
  }
  __syncthreads();
  int j = tid & 127, half = tid >> 7;
  float acc = 0.0f;
#pragma unroll 8
  for (int k = half * 64; k < half * 64 + 64; ++k)
    acc = fmaf(p[k], w1[k * 128 + j], acc);
  red[tid] = acc;
  __syncthreads();
  if (tid < 128) r[tid] = fmaxf(red[tid] + red[tid + 128] + b1[tid], 0.0f);
  __syncthreads();
  if (tid < 2) {
    float a = 0.0f;
    for (int k = 0; k < 128; ++k) a = fmaf(r[k], w2[k * 2 + tid], a);
    out[g * 2 + tid] = a + b2[tid];
  }
}

static inline size_t alup(size_t x) { return (x + 255) & ~(size_t)255; }

extern "C" void kernel_launch(void* const* d_in, const int* in_sizes, int n_in,
                              void* d_out, int out_size, void* d_ws, size_t ws_size,
                              hipStream_t stream) {
  const float* x    = (const float*)d_in[0];
  const int*   ei   = (const int*)d_in[1];
  const int*   bat  = (const int*)d_in[2];
  const float* W1   = (const float*)d_in[3];
  const float* b1   = (const float*)d_in[4];
  const float* ln1g = (const float*)d_in[5];
  const float* ln1b = (const float*)d_in[6];
  const float* W2   = (const float*)d_in[7];
  const float* b2   = (const float*)d_in[8];
  const float* ln2g = (const float*)d_in[9];
  const float* ln2b = (const float*)d_in[10];
  const float* gw1  = (const float*)d_in[11];
  const float* gb1  = (const float*)d_in[12];
  const float* gw2  = (const float*)d_in[13];
  const float* gb2  = (const float*)d_in[14];
  const float* cw1  = (const float*)d_in[15];
  const float* cb1  = (const float*)d_in[16];
  const float* cw2  = (const float*)d_in[17];
  const float* cb2  = (const float*)d_in[18];

  const int N = in_sizes[2];
  const int E = in_sizes[1] / 2;
  const int G = out_size / 2;
  const int* src = ei;
  const int* dst = ei + E;

  int nb256 = (N + 255) / 256;
  int eb256 = (E + 255) / 256;
  int mfmaB = (N + 63) / 64;
  int gatherB = (N + 15) / 16;

  char* base = (char*)d_ws;
  unsigned int* deg = (unsigned int*)base; base += alup((size_t)N * 4);
  float* dinv = (float*)base;              base += alup((size_t)N * 4);
  int* offs = (int*)base;                  base += alup((size_t)(N + 1) * 4);
  int* cursor = (int*)base;                base += alup((size_t)N * 4);
  int* partial = (int*)base;               base += alup((size_t)nb256 * 4);
  int2* col2 = (int2*)base;                base += alup((size_t)E * 8);
  unsigned short* pW = (unsigned short*)base; base += alup((size_t)3 * 32768 * 2);
  unsigned short* hbuf = (unsigned short*)base; base += alup((size_t)N * 128 * 2);
  unsigned short* hout = (unsigned short*)base; base += alup((size_t)N * 128 * 2);
  float* gate = (float*)base;              base += alup((size_t)N * 4);

  unsigned short* pW1 = pW;
  unsigned short* pW2 = pW + 32768;
  unsigned short* pG1 = pW + 65536;

  float* out = (float*)d_out;

  // ---- K1: pack weights + zero deg ----
  pack_zero<<<384 + nb256, 256, 0, stream>>>(W1, W2, gw1, pW, deg, N);
  // ---- degree & scan ----
  accum_deg<<<eb256, 256, 0, stream>>>(dst, deg, E);
  scanA<<<nb256, 256, 0, stream>>>(deg, offs, partial, dinv, N);
  scanC<<<nb256, 256, 0, stream>>>(offs, partial, cursor, N, E);
  // ---- K5: scatter CSR overlapped with layer-1 GEMM (both LDS-free) ----
  gemm1_scatter<<<mfmaB + eb256, 256, 0, stream>>>(x, pW1, hbuf, N,
                                                   src, dst, cursor, col2, dinv, E, mfmaB);
  // ---- layer 1 gather+LN ----
  gather_ln<<<gatherB, 256, 0, stream>>>(offs, col2, dinv, hbuf, b1, ln1g, ln1b, hout, N);
  // ---- layer 2 ----
  gemm_b16in<<<mfmaB, 256, 0, stream>>>(hout, pW2, hbuf, N);
  gather_ln<<<gatherB, 256, 0, stream>>>(offs, col2, dinv, hbuf, b2, ln2g, ln2b, hout, N);
  // ---- gate MLP (fused) ----
  gemm_gate<<<mfmaB, 256, 0, stream>>>(hout, pG1, gb1, gw2, gb2, gate, N);
  // ---- pooling + classifier ----
  pool_cls<<<G, 256, 0, stream>>>(gate, hout, bat, cw1, cb1, cw2, cb2, out, N);
}

// Round 12
// 266.021 us; speedup vs baseline: 5.6546x; 1.0242x over previous
//
#include <hip/hip_runtime.h>
#include <hip/hip_bf16.h>

typedef short s8v __attribute__((ext_vector_type(8)));
typedef float f4v __attribute__((ext_vector_type(4)));

#define LDA 136  // padded LDS row (shorts): 272B -> bank stride 4, 2-way max

// ---------- bf16 helpers ----------
__device__ __forceinline__ unsigned short f2bf(float f) {  // RNE
  unsigned int u = __builtin_bit_cast(unsigned int, f);
  unsigned int r = u + 0x7fffu + ((u >> 16) & 1u);
  return (unsigned short)(r >> 16);
}
__device__ __forceinline__ float bf2f(unsigned short s) {
  return __builtin_bit_cast(float, ((unsigned int)s) << 16);
}
__device__ __forceinline__ float bflo(unsigned int v) {
  return __builtin_bit_cast(float, (unsigned int)(v << 16));
}
__device__ __forceinline__ float bfhi(unsigned int v) {
  return __builtin_bit_cast(float, (unsigned int)(v & 0xffff0000u));
}
__device__ __forceinline__ unsigned int packbf(float a, float b) {
  return (unsigned int)f2bf(a) | ((unsigned int)f2bf(b) << 16);
}

__device__ __forceinline__ int lower_bound_i(const int* a, int n, int key) {
  int lo = 0, hi = n;
  while (lo < hi) { int mid = (lo + hi) >> 1; if (a[mid] < key) lo = mid + 1; else hi = mid; }
  return lo;
}

// ---------- gather one node group into v[8] (16 lanes x 8 features) ----------
__device__ __forceinline__ void gather_node(
    int i, int sub, const int* __restrict__ offs, const int2* __restrict__ col2,
    const float* __restrict__ dinv, const uint4* __restrict__ hu,
    const float* __restrict__ bias, float v[8]) {
  float di = dinv[i];
  float sl = di * di;
  uint4 hv = hu[(size_t)i * 16 + sub];
  float4 b0v = reinterpret_cast<const float4*>(bias)[sub * 2];
  float4 b1v = reinterpret_cast<const float4*>(bias)[sub * 2 + 1];
  v[0] = bflo(hv.x) * sl + b0v.x; v[1] = bfhi(hv.x) * sl + b0v.y;
  v[2] = bflo(hv.y) * sl + b0v.z; v[3] = bfhi(hv.y) * sl + b0v.w;
  v[4] = bflo(hv.z) * sl + b1v.x; v[5] = bfhi(hv.z) * sl + b1v.y;
  v[6] = bflo(hv.w) * sl + b1v.z; v[7] = bfhi(hv.w) * sl + b1v.w;
  int b0 = offs[i], b1 = offs[i + 1];
  int e = b0;
  for (; e + 4 <= b1; e += 4) {
    int2 c0 = col2[e], c1 = col2[e + 1], c2 = col2[e + 2], c3 = col2[e + 3];
    uint4 h0 = hu[(size_t)c0.x * 16 + sub];
    uint4 h1 = hu[(size_t)c1.x * 16 + sub];
    uint4 h2 = hu[(size_t)c2.x * 16 + sub];
    uint4 h3 = hu[(size_t)c3.x * 16 + sub];
    float n0 = __builtin_bit_cast(float, c0.y) * di;
    float n1 = __builtin_bit_cast(float, c1.y) * di;
    float n2 = __builtin_bit_cast(float, c2.y) * di;
    float n3 = __builtin_bit_cast(float, c3.y) * di;
    v[0] += bflo(h0.x) * n0 + bflo(h1.x) * n1 + bflo(h2.x) * n2 + bflo(h3.x) * n3;
    v[1] += bfhi(h0.x) * n0 + bfhi(h1.x) * n1 + bfhi(h2.x) * n2 + bfhi(h3.x) * n3;
    v[2] += bflo(h0.y) * n0 + bflo(h1.y) * n1 + bflo(h2.y) * n2 + bflo(h3.y) * n3;
    v[3] += bfhi(h0.y) * n0 + bfhi(h1.y) * n1 + bfhi(h2.y) * n2 + bfhi(h3.y) * n3;
    v[4] += bflo(h0.z) * n0 + bflo(h1.z) * n1 + bflo(h2.z) * n2 + bflo(h3.z) * n3;
    v[5] += bfhi(h0.z) * n0 + bfhi(h1.z) * n1 + bfhi(h2.z) * n2 + bfhi(h3.z) * n3;
    v[6] += bflo(h0.w) * n0 + bflo(h1.w) * n1 + bflo(h2.w) * n2 + bflo(h3.w) * n3;
    v[7] += bfhi(h0.w) * n0 + bfhi(h1.w) * n1 + bfhi(h2.w) * n2 + bfhi(h3.w) * n3;
  }
  for (; e < b1; ++e) {
    int2 c0 = col2[e];
    uint4 h0 = hu[(size_t)c0.x * 16 + sub];
    float n0 = __builtin_bit_cast(float, c0.y) * di;
    v[0] += bflo(h0.x) * n0; v[1] += bfhi(h0.x) * n0;
    v[2] += bflo(h0.y) * n0; v[3] += bfhi(h0.y) * n0;
    v[4] += bflo(h0.z) * n0; v[5] += bfhi(h0.z) * n0;
    v[6] += bflo(h0.w) * n0; v[7] += bfhi(h0.w) * n0;
  }
}

// LN across 16 lanes + relu + pack into uint4
__device__ __forceinline__ uint4 ln_relu_pack(
    float v[8], int sub, const float* __restrict__ gam, const float* __restrict__ bet) {
  float s = 0.f, q = 0.f;
#pragma unroll
  for (int j = 0; j < 8; ++j) { s += v[j]; q += v[j] * v[j]; }
#pragma unroll
  for (int o = 1; o < 16; o <<= 1) {
    s += __shfl_xor(s, o);
    q += __shfl_xor(q, o);
  }
  float m = s * (1.0f / 128.0f);
  float var = q * (1.0f / 128.0f) - m * m;
  float rs = rsqrtf(var + 1e-5f);
  float4 g0 = reinterpret_cast<const float4*>(gam)[sub * 2];
  float4 g1 = reinterpret_cast<const float4*>(gam)[sub * 2 + 1];
  float4 e0 = reinterpret_cast<const float4*>(bet)[sub * 2];
  float4 e1 = reinterpret_cast<const float4*>(bet)[sub * 2 + 1];
  uint4 ov;
  ov.x = packbf(fmaxf((v[0] - m) * rs * g0.x + e0.x, 0.f), fmaxf((v[1] - m) * rs * g0.y + e0.y, 0.f));
  ov.y = packbf(fmaxf((v[2] - m) * rs * g0.z + e0.z, 0.f), fmaxf((v[3] - m) * rs * g0.w + e0.w, 0.f));
  ov.z = packbf(fmaxf((v[4] - m) * rs * g1.x + e1.x, 0.f), fmaxf((v[5] - m) * rs * g1.y + e1.y, 0.f));
  ov.w = packbf(fmaxf((v[6] - m) * rs * g1.z + e1.z, 0.f), fmaxf((v[7] - m) * rs * g1.w + e1.w, 0.f));
  return ov;
}

// ---------- K1: weight pack (3x) + deg zeroing ----------
__global__ __launch_bounds__(256) void pack_zero(
    const float* __restrict__ Wa, const float* __restrict__ Wb, const float* __restrict__ Wc,
    unsigned short* __restrict__ P, unsigned int* __restrict__ deg, int n) {
  int bid = blockIdx.x;
  if (bid >= 384) {
    int i = (bid - 384) * 256 + threadIdx.x;
    if (i < n) deg[i] = 0u;
    return;
  }
  int gidx = bid * 256 + threadIdx.x;
  int which = gidx >> 15;
  int idx = gidx & 32767;
  const float* W = (which == 0) ? Wa : (which == 1) ? Wb : Wc;
  int j = idx & 15;
  int lane = (idx >> 4) & 63;
  int t = (idx >> 10) & 7;
  int c = (idx >> 13) & 3;
  int k = c * 32 + (lane >> 4) * 8 + (j & 7);
  int nn = t * 16 + (lane & 15);
  float f = W[k * 128 + nn];
  unsigned short hi = f2bf(f);
  unsigned short outv = (j < 8) ? hi : f2bf(f - bf2f(hi));
  P[gidx] = outv;
}

__global__ void accum_deg(const int* __restrict__ dst, unsigned int* __restrict__ deg, int E) {
  int e = blockIdx.x * blockDim.x + threadIdx.x;
  if (e < E) atomicAdd(&deg[dst[e]], 1u);
}

__global__ __launch_bounds__(256) void scanA(const unsigned int* __restrict__ deg,
                                             int* __restrict__ offs, int* __restrict__ partial,
                                             float* __restrict__ dinv, int n) {
  __shared__ int sh[256];
  int t = threadIdx.x;
  int i = blockIdx.x * 256 + t;
  int v = (i < n) ? (int)deg[i] : 0;
  if (i < n) dinv[i] = rsqrtf((float)(deg[i] + 1u));
  sh[t] = v;
  __syncthreads();
  for (int o = 1; o < 256; o <<= 1) {
    int add = (t >= o) ? sh[t - o] : 0;
    __syncthreads();
    sh[t] += add;
    __syncthreads();
  }
  if (i < n) offs[i] = sh[t] - v;
  if (t == 255) partial[blockIdx.x] = sh[255];
}

__global__ __launch_bounds__(256) void scanC(int* __restrict__ offs, const int* __restrict__ partial,
                                             int* __restrict__ cursor, int n, int E) {
  __shared__ int red[256];
  int bid = blockIdx.x;
  int t = threadIdx.x;
  int s = 0;
  for (int j = t; j < bid; j += 256) s += partial[j];
  red[t] = s;
  __syncthreads();
#pragma unroll
  for (int o = 128; o > 0; o >>= 1) {
    if (t < o) red[t] += red[t + o];
    __syncthreads();
  }
  int pre = red[0];
  int i = bid * 256 + t;
  if (i < n) {
    int o = offs[i] + pre;
    offs[i] = o;
    cursor[i] = o;
  }
  if (i == 0) offs[n] = E;
}

// ---------- K5: merged CSR scatter + layer-1 GEMM (LDS-free) ----------
__global__ __launch_bounds__(256) void gemm1_scatter(
    const float* __restrict__ in, const unsigned short* __restrict__ P,
    unsigned short* __restrict__ out, int n,
    const int* __restrict__ src, const int* __restrict__ dst,
    int* __restrict__ cursor, int2* __restrict__ col2,
    const float* __restrict__ dinv, int E, int gemmBlocks) {
  if ((int)blockIdx.x >= gemmBlocks) {
    int e = ((int)blockIdx.x - gemmBlocks) * 256 + threadIdx.x;
    if (e < E) {
      int d = dst[e];
      int s = src[e];
      int slot = atomicAdd(&cursor[d], 1);
      col2[slot] = make_int2(s, __builtin_bit_cast(int, dinv[s]));
    }
    return;
  }
  int tid = threadIdx.x;
  int wave = tid >> 6, lane = tid & 63;
  int quad = lane >> 4, col = lane & 15;
  int base = blockIdx.x * 64 + wave * 16;
  int m = base + col;

  f4v acc[8];
#pragma unroll
  for (int t = 0; t < 8; ++t) acc[t] = (f4v){0.f, 0.f, 0.f, 0.f};

  for (int c = 0; c < 4; ++c) {
    s8v ah, al;
    float v[8];
    if (m < n) {
      const float4* xp = reinterpret_cast<const float4*>(in + (size_t)m * 128 + c * 32 + quad * 8);
      float4 v0 = xp[0], v1 = xp[1];
      v[0] = v0.x; v[1] = v0.y; v[2] = v0.z; v[3] = v0.w;
      v[4] = v1.x; v[5] = v1.y; v[6] = v1.z; v[7] = v1.w;
    } else {
#pragma unroll
      for (int j = 0; j < 8; ++j) v[j] = 0.f;
    }
#pragma unroll
    for (int j = 0; j < 8; ++j) {
      unsigned short h = f2bf(v[j]);
      ah[j] = (short)h;
      al[j] = (short)f2bf(v[j] - bf2f(h));
    }
#pragma unroll
    for (int t = 0; t < 8; ++t) {
      const s8v* bp = reinterpret_cast<const s8v*>(&P[((c * 8 + t) * 64 + lane) * 16]);
      s8v bh = bp[0], bl = bp[1];
      acc[t] = __builtin_amdgcn_mfma_f32_16x16x32_bf16(ah, bh, acc[t], 0, 0, 0);
      acc[t] = __builtin_amdgcn_mfma_f32_16x16x32_bf16(ah, bl, acc[t], 0, 0, 0);
      acc[t] = __builtin_amdgcn_mfma_f32_16x16x32_bf16(al, bh, acc[t], 0, 0, 0);
    }
  }
#pragma unroll
  for (int t = 0; t < 8; ++t)
#pragma unroll
    for (int r = 0; r < 4; ++r) {
      int mm = base + quad * 4 + r;
      if (mm < n) out[(size_t)mm * 128 + t * 16 + col] = f2bf(acc[t][r]);
    }
}

// ---------- K6: fused gather1+LN -> LDS A-tile -> GEMM(W2) -> out ----------
// block = 256 threads, 64 nodes
__global__ __launch_bounds__(256) void gather_gemm(
    const int* __restrict__ offs, const int2* __restrict__ col2,
    const float* __restrict__ dinv, const unsigned short* __restrict__ h,
    const float* __restrict__ bias, const float* __restrict__ gam,
    const float* __restrict__ bet, const unsigned short* __restrict__ P,
    unsigned short* __restrict__ out, int n) {
  __shared__ unsigned short A[64 * LDA];
  int tid = threadIdx.x;
  int wave = tid >> 6, lane = tid & 63;
  int grp = lane >> 4, sub = lane & 15;
  const uint4* hu = reinterpret_cast<const uint4*>(h);
  int blk = blockIdx.x * 64;
  // gather phase: 4 iterations x (4 waves x 4 nodes)
  for (int it = 0; it < 4; ++it) {
    int li = it * 16 + wave * 4 + grp;
    int i = blk + li;
    uint4 ov;
    if (i < n) {
      float v[8];
      gather_node(i, sub, offs, col2, dinv, hu, bias, v);
      ov = ln_relu_pack(v, sub, gam, bet);
    } else {
      ov = make_uint4(0u, 0u, 0u, 0u);
    }
    *reinterpret_cast<uint4*>(&A[li * LDA + sub * 8]) = ov;
  }
  __syncthreads();
  // GEMM phase: wave handles rows wave*16 + col
  int quad = lane >> 4, col = lane & 15;
  f4v acc[8];
#pragma unroll
  for (int t = 0; t < 8; ++t) acc[t] = (f4v){0.f, 0.f, 0.f, 0.f};
  int liA = wave * 16 + col;
  for (int c = 0; c < 4; ++c) {
    s8v ah = *reinterpret_cast<const s8v*>(&A[liA * LDA + c * 32 + quad * 8]);
#pragma unroll
    for (int t = 0; t < 8; ++t) {
      const s8v* bp = reinterpret_cast<const s8v*>(&P[((c * 8 + t) * 64 + lane) * 16]);
      s8v bh = bp[0], bl = bp[1];
      acc[t] = __builtin_amdgcn_mfma_f32_16x16x32_bf16(ah, bh, acc[t], 0, 0, 0);
      acc[t] = __builtin_amdgcn_mfma_f32_16x16x32_bf16(ah, bl, acc[t], 0, 0, 0);
    }
  }
#pragma unroll
  for (int t = 0; t < 8; ++t)
#pragma unroll
    for (int r = 0; r < 4; ++r) {
      int mm = blk + wave * 16 + quad * 4 + r;
      if (mm < n) out[(size_t)mm * 128 + t * 16 + col] = f2bf(acc[t][r]);
    }
}

// ---------- K7: fused gather2+LN -> LDS + global hout -> gate GEMM -> gate[N] ----------
__global__ __launch_bounds__(256) void gather_gate(
    const int* __restrict__ offs, const int2* __restrict__ col2,
    const float* __restrict__ dinv, const unsigned short* __restrict__ h,
    const float* __restrict__ bias, const float* __restrict__ gam,
    const float* __restrict__ bet, const unsigned short* __restrict__ P,
    const float* __restrict__ gb1, const float* __restrict__ gw2,
    const float* __restrict__ gb2, unsigned short* __restrict__ hout,
    float* __restrict__ gate, int n) {
  __shared__ unsigned short A[64 * LDA];
  int tid = threadIdx.x;
  int wave = tid >> 6, lane = tid & 63;
  int grp = lane >> 4, sub = lane & 15;
  const uint4* hu = reinterpret_cast<const uint4*>(h);
  int blk = blockIdx.x * 64;
  for (int it = 0; it < 4; ++it) {
    int li = it * 16 + wave * 4 + grp;
    int i = blk + li;
    uint4 ov;
    if (i < n) {
      float v[8];
      gather_node(i, sub, offs, col2, dinv, hu, bias, v);
      ov = ln_relu_pack(v, sub, gam, bet);
      reinterpret_cast<uint4*>(hout)[(size_t)i * 16 + sub] = ov;
    } else {
      ov = make_uint4(0u, 0u, 0u, 0u);
    }
    *reinterpret_cast<uint4*>(&A[li * LDA + sub * 8]) = ov;
  }
  __syncthreads();
  int quad = lane >> 4, col = lane & 15;
  f4v acc[8];
#pragma unroll
  for (int t = 0; t < 8; ++t) acc[t] = (f4v){0.f, 0.f, 0.f, 0.f};
  int liA = wave * 16 + col;
  for (int c = 0; c < 4; ++c) {
    s8v ah = *reinterpret_cast<const s8v*>(&A[liA * LDA + c * 32 + quad * 8]);
#pragma unroll
    for (int t = 0; t < 8; ++t) {
      const s8v* bp = reinterpret_cast<const s8v*>(&P[((c * 8 + t) * 64 + lane) * 16]);
      s8v bh = bp[0], bl = bp[1];
      acc[t] = __builtin_amdgcn_mfma_f32_16x16x32_bf16(ah, bh, acc[t], 0, 0, 0);
      acc[t] = __builtin_amdgcn_mfma_f32_16x16x32_bf16(ah, bl, acc[t], 0, 0, 0);
    }
  }
  float bv[8], g2[8];
#pragma unroll
  for (int t = 0; t < 8; ++t) {
    bv[t] = gb1[t * 16 + col];
    g2[t] = gw2[t * 16 + col];
  }
  float gb2v = gb2[0];
#pragma unroll
  for (int r = 0; r < 4; ++r) {
    float p = 0.f;
#pragma unroll
    for (int t = 0; t < 8; ++t)
      p += fmaxf(acc[t][r] + bv[t], 0.f) * g2[t];
#pragma unroll
    for (int o = 1; o < 16; o <<= 1) p += __shfl_xor(p, o);
    int mm = blk + wave * 16 + quad * 4 + r;
    if (col == 0 && mm < n) gate[mm] = p + gb2v;
  }
}

// ---------- attention pooling + classifier fused ----------
__global__ __launch_bounds__(256) void pool_cls(
    float* __restrict__ gate, const unsigned short* __restrict__ h,
    const int* __restrict__ batch,
    const float* __restrict__ w1, const float* __restrict__ b1,
    const float* __restrict__ w2, const float* __restrict__ b2,
    float* __restrict__ out, int n) {
  int g = blockIdx.x;
  int tid = threadIdx.x;
  __shared__ float red[256];
  __shared__ float red2[256];
  __shared__ float p[128];
  __shared__ float r[128];
  int lo = lower_bound_i(batch, n, g);
  int hi = lower_bound_i(batch, n, g + 1);
  if (lo >= hi) {
    if (tid < 128) p[tid] = 0.0f;
  } else {
    float m = -3.0e38f;
    for (int i = lo + tid; i < hi; i += 256) m = fmaxf(m, gate[i]);
    red[tid] = m;
    __syncthreads();
#pragma unroll
    for (int o = 128; o > 0; o >>= 1) {
      if (tid < o) red[tid] = fmaxf(red[tid], red[tid + o]);
      __syncthreads();
    }
    m = red[0];
    __syncthreads();
    float s = 0.0f;
    for (int i = lo + tid; i < hi; i += 256) {
      float e = __expf(gate[i] - m);
      gate[i] = e;
      s += e;
    }
    red[tid] = s;
    __syncthreads();
#pragma unroll
    for (int o = 128; o > 0; o >>= 1) {
      if (tid < o) red[tid] += red[tid + o];
      __syncthreads();
    }
    float inv = 1.0f / red[0];
    __syncthreads();
    const unsigned int* hu = reinterpret_cast<const unsigned int*>(h);
    int j = tid & 63, rgp = tid >> 6;
    float a0 = 0.f, a1 = 0.f;
    int i = lo + rgp;
    for (; i + 4 < hi; i += 8) {
      unsigned int p0 = hu[(size_t)i * 64 + j];
      unsigned int p1 = hu[(size_t)(i + 4) * 64 + j];
      float w0 = gate[i], w1v = gate[i + 4];
      a0 += bflo(p0) * w0 + bflo(p1) * w1v;
      a1 += bfhi(p0) * w0 + bfhi(p1) * w1v;
    }
    if (i < hi) {
      unsigned int p0 = hu[(size_t)i * 64 + j];
      float w0 = gate[i];
      a0 += bflo(p0) * w0;
      a1 += bfhi(p0) * w0;
    }
    red[tid] = a0;
    red2[tid] = a1;
    __syncthreads();
    if (tid < 64) {
      p[2 * tid]     = (red[tid] + red[tid + 64] + red[tid + 128] + red[tid + 192]) * inv;
      p[2 * tid + 1] = (red2[tid] + red2[tid + 64] + red2[tid + 128] + red2[tid + 192]) * inv;
    }
  }
  __syncthreads();
  int j = tid & 127, half = tid >> 7;
  float acc = 0.0f;
#pragma unroll 8
  for (int k = half * 64; k < half * 64 + 64; ++k)
    acc = fmaf(p[k], w1[k * 128 + j], acc);
  red[tid] = acc;
  __syncthreads();
  if (tid < 128) r[tid] = fmaxf(red[tid] + red[tid + 128] + b1[tid], 0.0f);
  __syncthreads();
  if (tid < 2) {
    float a = 0.0f;
    for (int k = 0; k < 128; ++k) a = fmaf(r[k], w2[k * 2 + tid], a);
    out[g * 2 + tid] = a + b2[tid];
  }
}

static inline size_t alup(size_t x) { return (x + 255) & ~(size_t)255; }

extern "C" void kernel_launch(void* const* d_in, const int* in_sizes, int n_in,
                              void* d_out, int out_size, void* d_ws, size_t ws_size,
                              hipStream_t stream) {
  const float* x    = (const float*)d_in[0];
  const int*   ei   = (const int*)d_in[1];
  const int*   bat  = (const int*)d_in[2];
  const float* W1   = (const float*)d_in[3];
  const float* b1   = (const float*)d_in[4];
  const float* ln1g = (const float*)d_in[5];
  const float* ln1b = (const float*)d_in[6];
  const float* W2   = (const float*)d_in[7];
  const float* b2   = (const float*)d_in[8];
  const float* ln2g = (const float*)d_in[9];
  const float* ln2b = (const float*)d_in[10];
  const float* gw1  = (const float*)d_in[11];
  const float* gb1  = (const float*)d_in[12];
  const float* gw2  = (const float*)d_in[13];
  const float* gb2  = (const float*)d_in[14];
  const float* cw1  = (const float*)d_in[15];
  const float* cb1  = (const float*)d_in[16];
  const float* cw2  = (const float*)d_in[17];
  const float* cb2  = (const float*)d_in[18];

  const int N = in_sizes[2];
  const int E = in_sizes[1] / 2;
  const int G = out_size / 2;
  const int* src = ei;
  const int* dst = ei + E;

  int nb256 = (N + 255) / 256;
  int eb256 = (E + 255) / 256;
  int mfmaB = (N + 63) / 64;

  char* base = (char*)d_ws;
  unsigned int* deg = (unsigned int*)base; base += alup((size_t)N * 4);
  float* dinv = (float*)base;              base += alup((size_t)N * 4);
  int* offs = (int*)base;                  base += alup((size_t)(N + 1) * 4);
  int* cursor = (int*)base;                base += alup((size_t)N * 4);
  int* partial = (int*)base;               base += alup((size_t)nb256 * 4);
  int2* col2 = (int2*)base;                base += alup((size_t)E * 8);
  unsigned short* pW = (unsigned short*)base; base += alup((size_t)3 * 32768 * 2);
  unsigned short* hbuf = (unsigned short*)base;  base += alup((size_t)N * 128 * 2);
  unsigned short* hbuf2 = (unsigned short*)base; base += alup((size_t)N * 128 * 2);
  unsigned short* hout = (unsigned short*)base;  base += alup((size_t)N * 128 * 2);
  float* gate = (float*)base;              base += alup((size_t)N * 4);

  unsigned short* pW1 = pW;
  unsigned short* pW2 = pW + 32768;
  unsigned short* pG1 = pW + 65536;

  float* out = (float*)d_out;

  // ---- preamble: pack weights + zero deg; degree; scan ----
  pack_zero<<<384 + nb256, 256, 0, stream>>>(W1, W2, gw1, pW, deg, N);
  accum_deg<<<eb256, 256, 0, stream>>>(dst, deg, E);
  scanA<<<nb256, 256, 0, stream>>>(deg, offs, partial, dinv, N);
  scanC<<<nb256, 256, 0, stream>>>(offs, partial, cursor, N, E);
  // ---- layer-1 GEMM overlapped with CSR scatter ----
  gemm1_scatter<<<mfmaB + eb256, 256, 0, stream>>>(x, pW1, hbuf, N,
                                                   src, dst, cursor, col2, dinv, E, mfmaB);
  // ---- fused gather1+LN+GEMM(W2) ----
  gather_gemm<<<mfmaB, 256, 0, stream>>>(offs, col2, dinv, hbuf, b1, ln1g, ln1b,
                                         pW2, hbuf2, N);
  // ---- fused gather2+LN (+hout) + gate GEMM ----
  gather_gate<<<mfmaB, 256, 0, stream>>>(offs, col2, dinv, hbuf2, b2, ln2g, ln2b,
                                         pG1, gb1, gw2, gb2, hout, gate, N);
  // ---- pooling + classifier ----
  pool_cls<<<G, 256, 0, stream>>>(gate, hout, bat, cw1, cb1, cw2, cb2, out, N);
}